// Round 6
// baseline (726.551 us; speedup 1.0000x reference)
//
#include <hip/hip_runtime.h>
#include <hip/hip_bf16.h>

#define N_ 50000
#define E_ 800000
#define IN_ 128
#define OUT_ 128
#define ASSIGN_ 256
#define B_ 32
#define KTOT 256     // 2*IN
#define JTOT 384     // OUT + ASSIGN
#define HCHUNK 16
#define ACHUNK 32

typedef __attribute__((ext_vector_type(8))) short short8;
typedef __attribute__((ext_vector_type(4))) float f32x4;
typedef __attribute__((ext_vector_type(4))) unsigned short ushort4v;
typedef __attribute__((ext_vector_type(2))) unsigned short ushort2v;

struct HL { unsigned short h, l; };

__device__ inline unsigned short f2bf(float v) {
    union { float f; unsigned u; } a;
    a.f = v;
    unsigned r = a.u + 0x7fff + ((a.u >> 16) & 1);  // RNE
    return (unsigned short)(r >> 16);
}
__device__ inline float bf2f(unsigned short b) {
    union { unsigned u; float f; } a;
    a.u = ((unsigned)b) << 16;
    return a.f;
}
__device__ inline HL split2(float v) {
    HL r;
    r.h = f2bf(v);
    r.l = f2bf(v - bf2f(r.h));
    return r;
}

// ---------------- histogram: deg[dst]++ ----------------
__global__ void k_hist(const int* __restrict__ ei, int* __restrict__ deg) {
    int e = blockIdx.x * 256 + threadIdx.x;
    if (e < E_) atomicAdd(&deg[ei[E_ + e]], 1);
}

// ---------------- exclusive scan: deg -> rowStart/rowFill ----------------
#define SCAN_T 1024
__global__ void k_scan(const int* __restrict__ deg, int* __restrict__ rowStart,
                       int* __restrict__ rowFill) {
    __shared__ int sums[SCAN_T];
    int t = threadIdx.x;
    const int CHUNK = (N_ + SCAN_T - 1) / SCAN_T;  // 49
    int s0 = t * CHUNK;
    int local = 0;
    for (int i = 0; i < CHUNK; i++) {
        int idx = s0 + i;
        if (idx < N_) local += deg[idx];
    }
    sums[t] = local;
    __syncthreads();
    for (int off = 1; off < SCAN_T; off <<= 1) {
        int v = sums[t];
        int add = (t >= off) ? sums[t - off] : 0;
        __syncthreads();
        sums[t] = v + add;
        __syncthreads();
    }
    int run = (t == 0) ? 0 : sums[t - 1];
    for (int i = 0; i < CHUNK; i++) {
        int idx = s0 + i;
        if (idx < N_) {
            rowStart[idx] = run;
            rowFill[idx] = run;
            run += deg[idx];
        }
    }
    if (t == SCAN_T - 1) rowStart[N_] = sums[SCAN_T - 1];
}

// ---------------- scatter edges into CSR-by-dst ----------------
__global__ void k_scatter(const int* __restrict__ ei, int* __restrict__ rowFill,
                          int* __restrict__ csr_src) {
    int e = blockIdx.x * 256 + threadIdx.x;
    if (e >= E_) return;
    int s = ei[e], d = ei[E_ + e];
    int p = atomicAdd(&rowFill[d], 1);
    csr_src[p] = s;
}

// ---------------- neigh mean -> bf16 hi/lo (one wave per node) ------
__global__ __launch_bounds__(256) void k_agg(const float* __restrict__ x,
                                             const int* __restrict__ rowStart,
                                             const int* __restrict__ csr_src,
                                             unsigned short* __restrict__ nhi,
                                             unsigned short* __restrict__ nlo) {
    int node = blockIdx.x * 4 + (threadIdx.x >> 6);
    int lane = threadIdx.x & 63;
    if (node >= N_) return;
    int a = rowStart[node], bnd = rowStart[node + 1];
    float ax = 0.f, ay = 0.f;
    int j = a;
    for (; j + 1 < bnd; j += 2) {
        int s0 = csr_src[j], s1 = csr_src[j + 1];
        float2 v0 = *(const float2*)(x + s0 * 128 + lane * 2);
        float2 v1 = *(const float2*)(x + s1 * 128 + lane * 2);
        ax += v0.x + v1.x;
        ay += v0.y + v1.y;
    }
    if (j < bnd) {
        int s0 = csr_src[j];
        float2 v0 = *(const float2*)(x + s0 * 128 + lane * 2);
        ax += v0.x;
        ay += v0.y;
    }
    float inv = 1.0f / (float)max(bnd - a, 1);
    ax *= inv;
    ay *= inv;
    HL hx = split2(ax), hy = split2(ay);
    ushort2v h, l;
    h.x = hx.h; h.y = hy.h;
    l.x = hx.l; l.y = hy.l;
    *(ushort2v*)(nhi + node * 128 + lane * 2) = h;
    *(ushort2v*)(nlo + node * 128 + lane * 2) = l;
}

// ---------------- x -> bf16 hi/lo ----------------
__global__ __launch_bounds__(256) void k_convx(const float* __restrict__ x,
                                               unsigned short* __restrict__ xhi,
                                               unsigned short* __restrict__ xlo) {
    int i4 = (blockIdx.x * 256 + threadIdx.x) * 4;
    if (i4 >= N_ * 128) return;
    float4 v = *(const float4*)(x + i4);
    HL a = split2(v.x), b = split2(v.y), c = split2(v.z), d = split2(v.w);
    ushort4v h, l;
    h.x = a.h; h.y = b.h; h.z = c.h; h.w = d.h;
    l.x = a.l; l.y = b.l; l.z = c.l; l.w = d.l;
    *(ushort4v*)(xhi + i4) = h;
    *(ushort4v*)(xlo + i4) = l;
}

// ---------------- W transposed -> bf16 hi/lo WT[j][k], plus bias ----------------
__global__ void k_prep(const float* __restrict__ We, const float* __restrict__ be,
                       const float* __restrict__ Wp, const float* __restrict__ bp,
                       unsigned short* __restrict__ WThi, unsigned short* __restrict__ WTlo,
                       float* __restrict__ bias) {
    int idx = blockIdx.x * 256 + threadIdx.x;
    if (idx < JTOT * KTOT) {
        int j = idx / KTOT, k = idx - j * KTOT;
        float v = (j < 128) ? We[k * 128 + j] : Wp[k * 256 + (j - 128)];
        HL s = split2(v);
        WThi[idx] = s.h;
        WTlo[idx] = s.l;
    }
    if (idx < JTOT) bias[idx] = (idx < 128) ? be[idx] : bp[idx - 128];
}

// ---------------- MFMA GEMM (bf16x3 split): [x|neigh] (N x 256) @ W (256 x 384) ----------------
// block tile 128x128, 4 waves (2x2), wave tile 64x64 = 4x4 mfma_16x16x32 tiles, BK=32
#define LDA 40  // row stride in ushorts: 80 B -> 16B-aligned rows, 2-way bank alias only
__global__ __launch_bounds__(256) void k_gemm(const unsigned short* __restrict__ xhi,
                                              const unsigned short* __restrict__ xlo,
                                              const unsigned short* __restrict__ nhi,
                                              const unsigned short* __restrict__ nlo,
                                              const unsigned short* __restrict__ WThi,
                                              const unsigned short* __restrict__ WTlo,
                                              const float* __restrict__ bias,
                                              float* __restrict__ embed,
                                              float* __restrict__ plog) {
    __shared__ unsigned short Ah[128][LDA], Al[128][LDA], Bh[128][LDA], Bl[128][LDA];
    int t = threadIdx.x;
    int wave = t >> 6, lane = t & 63;
    int wm = wave >> 1, wn = wave & 1;
    int q = lane >> 4, lr = lane & 15;
    int row0 = blockIdx.x * 128;
    int col0 = blockIdx.y * 128;

    f32x4 acc[4][4] = {};

    int sm = t >> 1;             // 0..127: row within tile
    int kc = (t & 1) * 16;       // 0 or 16

    for (int kt = 0; kt < KTOT; kt += 32) {
        const unsigned short* Ah_src = (kt < 128) ? xhi : nhi;
        const unsigned short* Al_src = (kt < 128) ? xlo : nlo;
        int kb = (kt & 127) + kc;
        int node = row0 + sm;
        short8 vh0 = {}, vh1 = {}, vl0 = {}, vl1 = {};
        if (node < N_) {
            const short8* ph = (const short8*)(Ah_src + (size_t)node * 128 + kb);
            const short8* pl = (const short8*)(Al_src + (size_t)node * 128 + kb);
            vh0 = ph[0]; vh1 = ph[1];
            vl0 = pl[0]; vl1 = pl[1];
        }
        *(short8*)&Ah[sm][kc] = vh0;
        *(short8*)&Ah[sm][kc + 8] = vh1;
        *(short8*)&Al[sm][kc] = vl0;
        *(short8*)&Al[sm][kc + 8] = vl1;
        {
            int j = col0 + sm;
            const short8* ph = (const short8*)(WThi + (size_t)j * 256 + kt + kc);
            const short8* pl = (const short8*)(WTlo + (size_t)j * 256 + kt + kc);
            short8 wh0 = ph[0], wh1 = ph[1];
            short8 wl0 = pl[0], wl1 = pl[1];
            *(short8*)&Bh[sm][kc] = wh0;
            *(short8*)&Bh[sm][kc + 8] = wh1;
            *(short8*)&Bl[sm][kc] = wl0;
            *(short8*)&Bl[sm][kc + 8] = wl1;
        }
        __syncthreads();

        short8 afh[4], afl[4];
#pragma unroll
        for (int mi = 0; mi < 4; mi++) {
            int r = wm * 64 + mi * 16 + lr;
            afh[mi] = *(const short8*)&Ah[r][q * 8];
            afl[mi] = *(const short8*)&Al[r][q * 8];
        }
#pragma unroll
        for (int ni = 0; ni < 4; ni++) {
            int r = wn * 64 + ni * 16 + lr;
            short8 bfh = *(const short8*)&Bh[r][q * 8];
            short8 bfl = *(const short8*)&Bl[r][q * 8];
#pragma unroll
            for (int mi = 0; mi < 4; mi++) {
                acc[mi][ni] = __builtin_amdgcn_mfma_f32_16x16x32_bf16(afh[mi], bfh, acc[mi][ni], 0, 0, 0);
                acc[mi][ni] = __builtin_amdgcn_mfma_f32_16x16x32_bf16(afh[mi], bfl, acc[mi][ni], 0, 0, 0);
                acc[mi][ni] = __builtin_amdgcn_mfma_f32_16x16x32_bf16(afl[mi], bfh, acc[mi][ni], 0, 0, 0);
            }
        }
        __syncthreads();
    }

    // epilogue: C/D layout col=lane&15, row=(lane>>4)*4+reg
#pragma unroll
    for (int ni = 0; ni < 4; ni++) {
        int col = col0 + wn * 64 + ni * 16 + lr;
        float bj = bias[col];
#pragma unroll
        for (int mi = 0; mi < 4; mi++) {
            int rbase = row0 + wm * 64 + mi * 16 + q * 4;
#pragma unroll
            for (int r = 0; r < 4; r++) {
                int row = rbase + r;
                if (row >= N_) continue;
                float v = acc[mi][ni][r] + bj;
                if (col < 128)
                    embed[(size_t)row * 128 + col] = v;
                else
                    plog[(size_t)row * 256 + (col - 128)] = v;
            }
        }
    }
}

// ---------------- double softmax -> compact r8[N][8] ----------------
__global__ __launch_bounds__(256) void k_r(const float* __restrict__ plog,
                                           const int* __restrict__ batch,
                                           float* __restrict__ r8) {
    int node = blockIdx.x * 4 + (threadIdx.x >> 6);
    int lane = threadIdx.x & 63;
    if (node >= N_) return;
    float4 p = *(const float4*)(plog + node * 256 + lane * 4);
    float m = fmaxf(fmaxf(p.x, p.y), fmaxf(p.z, p.w));
    for (int off = 32; off; off >>= 1) m = fmaxf(m, __shfl_xor(m, off, 64));
    float s = expf(p.x - m) + expf(p.y - m) + expf(p.z - m) + expf(p.w - m);
    for (int off = 32; off; off >>= 1) s += __shfl_xor(s, off, 64);
    int g = batch[node];
    float v = 0.f;
    if (lane < 8) v = expf(plog[node * 256 + g * 8 + lane] - m) / s;
    float M2 = v;
    for (int off = 4; off; off >>= 1) M2 = fmaxf(M2, __shfl_xor(M2, off, 64));
    float e = expf(v - M2);
    float Sg = e;
    for (int off = 4; off; off >>= 1) Sg += __shfl_xor(Sg, off, 64);
    float D2 = Sg + 248.0f * expf(-M2);
    float r = e / (Sg + 1e-13f * D2);
    if (lane < 8) r8[node * 8 + lane] = r;
}

// ---------------- h partials ----------------
__global__ __launch_bounds__(256) void k_h_part(const float* __restrict__ embed,
                                                const float* __restrict__ r8,
                                                float* __restrict__ partH) {
    int g = blockIdx.x;
    int c = blockIdx.y;
    int t = threadIdx.x;
    int o = t & 127, half = t >> 7;
    int n0g = (g * N_ + 31) >> 5;
    int n1g = ((g + 1) * N_ + 31) >> 5;
    int len = n1g - n0g;
    int a = n0g + (len * c) / HCHUNK;
    int b = n0g + (len * (c + 1)) / HCHUNK;
    float a0 = 0.f, a1 = 0.f, a2 = 0.f, a3 = 0.f;
#pragma unroll 4
    for (int n = a; n < b; n++) {
        float e = embed[n * 128 + o];
        const float* rr = r8 + n * 8 + half;
        a0 += rr[0] * e;
        a1 += rr[2] * e;
        a2 += rr[4] * e;
        a3 += rr[6] * e;
    }
    float* pb = partH + (g * HCHUNK + c) * 1024;
    pb[(half + 0) * 128 + o] = a0;
    pb[(half + 2) * 128 + o] = a1;
    pb[(half + 4) * 128 + o] = a2;
    pb[(half + 6) * 128 + o] = a3;
}

// ---------------- h reduce ----------------
__global__ __launch_bounds__(256) void k_h_red(const float* __restrict__ partH,
                                               float* __restrict__ out_h) {
    int idx = blockIdx.x * 256 + threadIdx.x;
    if (idx >= 256 * 128) return;
    int g = idx >> 10;
    int local = idx & 1023;
    float s = 0.f;
#pragma unroll
    for (int c = 0; c < HCHUNK; c++) s += partH[(g * HCHUNK + c) * 1024 + local];
    out_h[idx] = s;
}

// ---------------- adj partials from CSR (LDS atomic, fire-and-forget) ----------------
__global__ __launch_bounds__(256) void k_adj(const int* __restrict__ rowStart,
                                             const int* __restrict__ csr_src,
                                             const float* __restrict__ r8,
                                             float* __restrict__ partAdj) {
    __shared__ float lacc[2048];
    int gd = blockIdx.x;
    int c = blockIdx.y;
    int t = threadIdx.x;
    int w = t >> 6, lane = t & 63;
    int a = lane >> 3, b = lane & 7;
    for (int i = t; i < 2048; i += 256) lacc[i] = 0.f;
    __syncthreads();
    int n0g = (gd * N_ + 31) >> 5;
    int n1g = ((gd + 1) * N_ + 31) >> 5;
    int len = n1g - n0g;
    int na = n0g + (len * c) / ACHUNK;
    int nb = n0g + (len * (c + 1)) / ACHUNK;
    for (int n = na + w; n < nb; n += 4) {
        float rd = r8[n * 8 + b];
        int j0 = rowStart[n], j1 = rowStart[n + 1];
        int j = j0;
        for (; j + 3 < j1; j += 4) {
            int s0 = csr_src[j], s1 = csr_src[j + 1];
            int s2 = csr_src[j + 2], s3 = csr_src[j + 3];
            float v0 = r8[s0 * 8 + a], v1 = r8[s1 * 8 + a];
            float v2 = r8[s2 * 8 + a], v3 = r8[s3 * 8 + a];
            int g0 = (s0 * B_) / N_, g1 = (s1 * B_) / N_;
            int g2 = (s2 * B_) / N_, g3 = (s3 * B_) / N_;
            atomicAdd(&lacc[g0 * 64 + lane], v0 * rd);
            atomicAdd(&lacc[g1 * 64 + lane], v1 * rd);
            atomicAdd(&lacc[g2 * 64 + lane], v2 * rd);
            atomicAdd(&lacc[g3 * 64 + lane], v3 * rd);
        }
        for (; j < j1; j++) {
            int s = csr_src[j];
            int gs = (s * B_) / N_;
            atomicAdd(&lacc[gs * 64 + lane], r8[s * 8 + a] * rd);
        }
    }
    __syncthreads();
    float* pb = partAdj + (gd * ACHUNK + c) * 2048;
    for (int i = t; i < 2048; i += 256) pb[i] = lacc[i];
}

// ---------------- adj reduce ----------------
__global__ __launch_bounds__(256) void k_adj_red(const float* __restrict__ partAdj,
                                                 float* __restrict__ adj) {
    int o = blockIdx.x * 256 + threadIdx.x;
    if (o >= 256 * 256) return;
    int row = o >> 8, col = o & 255;
    int gs = row >> 3, a = row & 7;
    int gd = col >> 3, b = col & 7;
    int li = gs * 64 + a * 8 + b;
    float s = 0.f;
#pragma unroll
    for (int c = 0; c < ACHUNK; c++) s += partAdj[(gd * ACHUNK + c) * 2048 + li];
    adj[o] = s;
}

extern "C" void kernel_launch(void* const* d_in, const int* in_sizes, int n_in,
                              void* d_out, int out_size, void* d_ws, size_t ws_size,
                              hipStream_t stream) {
    const float* x = (const float*)d_in[0];
    const int* ei = (const int*)d_in[1];
    const int* batch = (const int*)d_in[2];
    const float* We = (const float*)d_in[3];
    const float* be = (const float*)d_in[4];
    const float* Wp = (const float*)d_in[5];
    const float* bp = (const float*)d_in[6];
    float* out = (float*)d_out;  // [adj 256*256 | h 256*128]

    char* w = (char*)d_ws;
    auto alloc = [&](size_t bytes) -> char* {
        char* p = w;
        w += (bytes + 255) & ~(size_t)255;
        return p;
    };
    unsigned short* xhi = (unsigned short*)alloc((size_t)N_ * 128 * 2);
    unsigned short* xlo = (unsigned short*)alloc((size_t)N_ * 128 * 2);
    unsigned short* nhi = (unsigned short*)alloc((size_t)N_ * 128 * 2);
    unsigned short* nlo = (unsigned short*)alloc((size_t)N_ * 128 * 2);
    unsigned short* WThi = (unsigned short*)alloc((size_t)JTOT * KTOT * 2);
    unsigned short* WTlo = (unsigned short*)alloc((size_t)JTOT * KTOT * 2);
    float* embed = (float*)alloc((size_t)N_ * 128 * 4);
    float* plog = (float*)alloc((size_t)N_ * 256 * 4);
    float* r8 = (float*)alloc((size_t)N_ * 8 * 4);
    float* bias = (float*)alloc(JTOT * 4);
    int* deg = (int*)alloc((size_t)N_ * 4);
    int* rowStart = (int*)alloc((size_t)(N_ + 1) * 4);
    int* rowFill = (int*)alloc((size_t)N_ * 4);
    int* csr_src = (int*)alloc((size_t)E_ * 4);
    float* partH = (float*)alloc((size_t)B_ * HCHUNK * 1024 * 4);
    float* partAdj = (float*)alloc((size_t)B_ * ACHUNK * 2048 * 4);

    (void)hipMemsetAsync(deg, 0, (size_t)N_ * 4, stream);

    k_hist<<<(E_ + 255) / 256, 256, 0, stream>>>(ei, deg);
    k_scan<<<1, SCAN_T, 0, stream>>>(deg, rowStart, rowFill);
    k_scatter<<<(E_ + 255) / 256, 256, 0, stream>>>(ei, rowFill, csr_src);
    k_convx<<<(N_ * 128 / 4 + 255) / 256, 256, 0, stream>>>(x, xhi, xlo);
    k_agg<<<(N_ + 3) / 4, 256, 0, stream>>>(x, rowStart, csr_src, nhi, nlo);
    k_prep<<<(JTOT * KTOT + 255) / 256, 256, 0, stream>>>(We, be, Wp, bp, WThi, WTlo, bias);
    dim3 gg((N_ + 127) / 128, JTOT / 128);
    k_gemm<<<gg, 256, 0, stream>>>(xhi, xlo, nhi, nlo, WThi, WTlo, bias, embed, plog);
    k_r<<<(N_ + 3) / 4, 256, 0, stream>>>(plog, batch, r8);
    dim3 hg(B_, HCHUNK);
    k_h_part<<<hg, 256, 0, stream>>>(embed, r8, partH);
    k_h_red<<<(256 * 128 + 255) / 256, 256, 0, stream>>>(partH, out + 256 * 256);
    dim3 ag(B_, ACHUNK);
    k_adj<<<ag, 256, 0, stream>>>(rowStart, csr_src, r8, partAdj);
    k_adj_red<<<(256 * 256 + 255) / 256, 256, 0, stream>>>(partAdj, out);
}

// Round 7
// 477.474 us; speedup vs baseline: 1.5217x; 1.5217x over previous
//
#include <hip/hip_runtime.h>
#include <hip/hip_bf16.h>

#define N_ 50000
#define E_ 800000
#define IN_ 128
#define OUT_ 128
#define ASSIGN_ 256
#define B_ 32
#define KTOT 256     // 2*IN
#define JTOT 384     // OUT + ASSIGN
#define HCHUNK 16
#define ACHUNK 16
#define AST 72       // LDS row stride in u16 (144 B: 16B-aligned, bank-spread)

typedef __attribute__((ext_vector_type(8))) short short8;
typedef __attribute__((ext_vector_type(4))) float f32x4;
typedef __attribute__((ext_vector_type(4))) unsigned short ushort4v;
typedef __attribute__((ext_vector_type(2))) unsigned short ushort2v;

struct HL { unsigned short h, l; };

__device__ inline unsigned short f2bf(float v) {
    union { float f; unsigned u; } a;
    a.f = v;
    unsigned r = a.u + 0x7fff + ((a.u >> 16) & 1);  // RNE
    return (unsigned short)(r >> 16);
}
__device__ inline float bf2f(unsigned short b) {
    union { unsigned u; float f; } a;
    a.u = ((unsigned)b) << 16;
    return a.f;
}
__device__ inline HL split2(float v) {
    HL r;
    r.h = f2bf(v);
    r.l = f2bf(v - bf2f(r.h));
    return r;
}

// ---------------- histogram: deg[dst]++ ----------------
__global__ void k_hist(const int* __restrict__ ei, int* __restrict__ deg) {
    int e = blockIdx.x * 256 + threadIdx.x;
    if (e < E_) atomicAdd(&deg[ei[E_ + e]], 1);
}

// ---------------- exclusive scan: deg -> rowStart/rowFill ----------------
#define SCAN_T 1024
__global__ void k_scan(const int* __restrict__ deg, int* __restrict__ rowStart,
                       int* __restrict__ rowFill) {
    __shared__ int sums[SCAN_T];
    int t = threadIdx.x;
    const int CHUNK = (N_ + SCAN_T - 1) / SCAN_T;  // 49
    int s0 = t * CHUNK;
    int local = 0;
    for (int i = 0; i < CHUNK; i++) {
        int idx = s0 + i;
        if (idx < N_) local += deg[idx];
    }
    sums[t] = local;
    __syncthreads();
    for (int off = 1; off < SCAN_T; off <<= 1) {
        int v = sums[t];
        int add = (t >= off) ? sums[t - off] : 0;
        __syncthreads();
        sums[t] = v + add;
        __syncthreads();
    }
    int run = (t == 0) ? 0 : sums[t - 1];
    for (int i = 0; i < CHUNK; i++) {
        int idx = s0 + i;
        if (idx < N_) {
            rowStart[idx] = run;
            rowFill[idx] = run;
            run += deg[idx];
        }
    }
    if (t == SCAN_T - 1) rowStart[N_] = sums[SCAN_T - 1];
}

// ---------------- scatter edges into CSR-by-dst (src and dst arrays) ----------------
__global__ void k_scatter(const int* __restrict__ ei, int* __restrict__ rowFill,
                          int* __restrict__ csr_src, int* __restrict__ csr_dst) {
    int e = blockIdx.x * 256 + threadIdx.x;
    if (e >= E_) return;
    int s = ei[e], d = ei[E_ + e];
    int p = atomicAdd(&rowFill[d], 1);
    csr_src[p] = s;
    csr_dst[p] = d;
}

// ---------------- neigh mean -> bf16 hi/lo (one wave per node) ------
__global__ __launch_bounds__(256) void k_agg(const float* __restrict__ x,
                                             const int* __restrict__ rowStart,
                                             const int* __restrict__ csr_src,
                                             unsigned short* __restrict__ nhi,
                                             unsigned short* __restrict__ nlo) {
    int node = blockIdx.x * 4 + (threadIdx.x >> 6);
    int lane = threadIdx.x & 63;
    if (node >= N_) return;
    int a = rowStart[node], bnd = rowStart[node + 1];
    float ax = 0.f, ay = 0.f;
    int j = a;
    for (; j + 1 < bnd; j += 2) {
        int s0 = csr_src[j], s1 = csr_src[j + 1];
        float2 v0 = *(const float2*)(x + s0 * 128 + lane * 2);
        float2 v1 = *(const float2*)(x + s1 * 128 + lane * 2);
        ax += v0.x + v1.x;
        ay += v0.y + v1.y;
    }
    if (j < bnd) {
        int s0 = csr_src[j];
        float2 v0 = *(const float2*)(x + s0 * 128 + lane * 2);
        ax += v0.x;
        ay += v0.y;
    }
    float inv = 1.0f / (float)max(bnd - a, 1);
    ax *= inv;
    ay *= inv;
    HL hx = split2(ax), hy = split2(ay);
    ushort2v h, l;
    h.x = hx.h; h.y = hy.h;
    l.x = hx.l; l.y = hy.l;
    *(ushort2v*)(nhi + node * 128 + lane * 2) = h;
    *(ushort2v*)(nlo + node * 128 + lane * 2) = l;
}

// ---------------- x -> bf16 hi/lo ----------------
__global__ __launch_bounds__(256) void k_convx(const float* __restrict__ x,
                                               unsigned short* __restrict__ xhi,
                                               unsigned short* __restrict__ xlo) {
    int i4 = (blockIdx.x * 256 + threadIdx.x) * 4;
    if (i4 >= N_ * 128) return;
    float4 v = *(const float4*)(x + i4);
    HL a = split2(v.x), b = split2(v.y), c = split2(v.z), d = split2(v.w);
    ushort4v h, l;
    h.x = a.h; h.y = b.h; h.z = c.h; h.w = d.h;
    l.x = a.l; l.y = b.l; l.z = c.l; l.w = d.l;
    *(ushort4v*)(xhi + i4) = h;
    *(ushort4v*)(xlo + i4) = l;
}

// ---------------- W transposed -> bf16 hi/lo WT[j][k], plus bias ----------------
__global__ void k_prep(const float* __restrict__ We, const float* __restrict__ be,
                       const float* __restrict__ Wp, const float* __restrict__ bp,
                       unsigned short* __restrict__ WThi, unsigned short* __restrict__ WTlo,
                       float* __restrict__ bias) {
    int idx = blockIdx.x * 256 + threadIdx.x;
    if (idx < JTOT * KTOT) {
        int j = idx / KTOT, k = idx - j * KTOT;
        float v = (j < 128) ? We[k * 128 + j] : Wp[k * 256 + (j - 128)];
        HL s = split2(v);
        WThi[idx] = s.h;
        WTlo[idx] = s.l;
    }
    if (idx < JTOT) bias[idx] = (idx < 128) ? be[idx] : bp[idx - 128];
}

// ---------------- MFMA GEMM (bf16x3 split): [x|neigh] (N x 256) @ W (256 x 384) ----------------
#define LDA 40
__global__ __launch_bounds__(256) void k_gemm(const unsigned short* __restrict__ xhi,
                                              const unsigned short* __restrict__ xlo,
                                              const unsigned short* __restrict__ nhi,
                                              const unsigned short* __restrict__ nlo,
                                              const unsigned short* __restrict__ WThi,
                                              const unsigned short* __restrict__ WTlo,
                                              const float* __restrict__ bias,
                                              float* __restrict__ embed,
                                              float* __restrict__ plog) {
    __shared__ unsigned short Ah[128][LDA], Al[128][LDA], Bh[128][LDA], Bl[128][LDA];
    int t = threadIdx.x;
    int wave = t >> 6, lane = t & 63;
    int wm = wave >> 1, wn = wave & 1;
    int q = lane >> 4, lr = lane & 15;
    int row0 = blockIdx.x * 128;
    int col0 = blockIdx.y * 128;

    f32x4 acc[4][4] = {};

    int sm = t >> 1;
    int kc = (t & 1) * 16;

    for (int kt = 0; kt < KTOT; kt += 32) {
        const unsigned short* Ah_src = (kt < 128) ? xhi : nhi;
        const unsigned short* Al_src = (kt < 128) ? xlo : nlo;
        int kb = (kt & 127) + kc;
        int node = row0 + sm;
        short8 vh0 = {}, vh1 = {}, vl0 = {}, vl1 = {};
        if (node < N_) {
            const short8* ph = (const short8*)(Ah_src + (size_t)node * 128 + kb);
            const short8* pl = (const short8*)(Al_src + (size_t)node * 128 + kb);
            vh0 = ph[0]; vh1 = ph[1];
            vl0 = pl[0]; vl1 = pl[1];
        }
        *(short8*)&Ah[sm][kc] = vh0;
        *(short8*)&Ah[sm][kc + 8] = vh1;
        *(short8*)&Al[sm][kc] = vl0;
        *(short8*)&Al[sm][kc + 8] = vl1;
        {
            int j = col0 + sm;
            const short8* ph = (const short8*)(WThi + (size_t)j * 256 + kt + kc);
            const short8* pl = (const short8*)(WTlo + (size_t)j * 256 + kt + kc);
            short8 wh0 = ph[0], wh1 = ph[1];
            short8 wl0 = pl[0], wl1 = pl[1];
            *(short8*)&Bh[sm][kc] = wh0;
            *(short8*)&Bh[sm][kc + 8] = wh1;
            *(short8*)&Bl[sm][kc] = wl0;
            *(short8*)&Bl[sm][kc + 8] = wl1;
        }
        __syncthreads();

        short8 afh[4], afl[4];
#pragma unroll
        for (int mi = 0; mi < 4; mi++) {
            int r = wm * 64 + mi * 16 + lr;
            afh[mi] = *(const short8*)&Ah[r][q * 8];
            afl[mi] = *(const short8*)&Al[r][q * 8];
        }
#pragma unroll
        for (int ni = 0; ni < 4; ni++) {
            int r = wn * 64 + ni * 16 + lr;
            short8 bfh = *(const short8*)&Bh[r][q * 8];
            short8 bfl = *(const short8*)&Bl[r][q * 8];
#pragma unroll
            for (int mi = 0; mi < 4; mi++) {
                acc[mi][ni] = __builtin_amdgcn_mfma_f32_16x16x32_bf16(afh[mi], bfh, acc[mi][ni], 0, 0, 0);
                acc[mi][ni] = __builtin_amdgcn_mfma_f32_16x16x32_bf16(afh[mi], bfl, acc[mi][ni], 0, 0, 0);
                acc[mi][ni] = __builtin_amdgcn_mfma_f32_16x16x32_bf16(afl[mi], bfh, acc[mi][ni], 0, 0, 0);
            }
        }
        __syncthreads();
    }

#pragma unroll
    for (int ni = 0; ni < 4; ni++) {
        int col = col0 + wn * 64 + ni * 16 + lr;
        float bj = bias[col];
#pragma unroll
        for (int mi = 0; mi < 4; mi++) {
            int rbase = row0 + wm * 64 + mi * 16 + q * 4;
#pragma unroll
            for (int r = 0; r < 4; r++) {
                int row = rbase + r;
                if (row >= N_) continue;
                float v = acc[mi][ni][r] + bj;
                if (col < 128)
                    embed[(size_t)row * 128 + col] = v;
                else
                    plog[(size_t)row * 256 + (col - 128)] = v;
            }
        }
    }
}

// ---------------- double softmax -> compact r8[N][8] (fp32 + bf16 copy) ----------------
__global__ __launch_bounds__(256) void k_r(const float* __restrict__ plog,
                                           const int* __restrict__ batch,
                                           float* __restrict__ r8,
                                           unsigned short* __restrict__ r8b) {
    int node = blockIdx.x * 4 + (threadIdx.x >> 6);
    int lane = threadIdx.x & 63;
    if (node >= N_) return;
    float4 p = *(const float4*)(plog + node * 256 + lane * 4);
    float m = fmaxf(fmaxf(p.x, p.y), fmaxf(p.z, p.w));
    for (int off = 32; off; off >>= 1) m = fmaxf(m, __shfl_xor(m, off, 64));
    float s = expf(p.x - m) + expf(p.y - m) + expf(p.z - m) + expf(p.w - m);
    for (int off = 32; off; off >>= 1) s += __shfl_xor(s, off, 64);
    int g = batch[node];
    float v = 0.f;
    if (lane < 8) v = expf(plog[node * 256 + g * 8 + lane] - m) / s;
    float M2 = v;
    for (int off = 4; off; off >>= 1) M2 = fmaxf(M2, __shfl_xor(M2, off, 64));
    float e = expf(v - M2);
    float Sg = e;
    for (int off = 4; off; off >>= 1) Sg += __shfl_xor(Sg, off, 64);
    float D2 = Sg + 248.0f * expf(-M2);
    float r = e / (Sg + 1e-13f * D2);
    if (lane < 8) {
        r8[node * 8 + lane] = r;
        r8b[node * 8 + lane] = f2bf(r);
    }
}

// ---------------- h partials ----------------
__global__ __launch_bounds__(256) void k_h_part(const float* __restrict__ embed,
                                                const float* __restrict__ r8,
                                                float* __restrict__ partH) {
    int g = blockIdx.x;
    int c = blockIdx.y;
    int t = threadIdx.x;
    int o = t & 127, half = t >> 7;
    int n0g = (g * N_ + 31) >> 5;
    int n1g = ((g + 1) * N_ + 31) >> 5;
    int len = n1g - n0g;
    int a = n0g + (len * c) / HCHUNK;
    int b = n0g + (len * (c + 1)) / HCHUNK;
    float a0 = 0.f, a1 = 0.f, a2 = 0.f, a3 = 0.f;
#pragma unroll 4
    for (int n = a; n < b; n++) {
        float e = embed[n * 128 + o];
        const float* rr = r8 + n * 8 + half;
        a0 += rr[0] * e;
        a1 += rr[2] * e;
        a2 += rr[4] * e;
        a3 += rr[6] * e;
    }
    float* pb = partH + (g * HCHUNK + c) * 1024;
    pb[(half + 0) * 128 + o] = a0;
    pb[(half + 2) * 128 + o] = a1;
    pb[(half + 4) * 128 + o] = a2;
    pb[(half + 6) * 128 + o] = a3;
}

// ---------------- h reduce ----------------
__global__ __launch_bounds__(256) void k_h_red(const float* __restrict__ partH,
                                               float* __restrict__ out_h) {
    int idx = blockIdx.x * 256 + threadIdx.x;
    if (idx >= 256 * 128) return;
    int g = idx >> 10;
    int local = idx & 1023;
    float s = 0.f;
#pragma unroll
    for (int c = 0; c < HCHUNK; c++) s += partH[(g * HCHUNK + c) * 1024 + local];
    out_h[idx] = s;
}

// ---------------- adj via MFMA over edge tiles ----------------
// Block (gd, c): nodes [na,nb) of graph gd -> contiguous CSR edge range [j0,j1).
// Per 64-edge K-tile: A[256][64] bf16 = gs-placed r8b[src] (zero-filled, scatter
// writes only, NO RMW); B[16][64] = r8b[dst] (rows 8..15 zero). MFMA contracts
// over edges: partial adj cols (256 x 8) accumulate in AGPRs.
__global__ __launch_bounds__(256) void k_adjm(const int* __restrict__ rowStart,
                                              const int* __restrict__ csr_src,
                                              const int* __restrict__ csr_dst,
                                              const unsigned short* __restrict__ r8b,
                                              float* __restrict__ partAdj) {
    __shared__ __align__(16) unsigned short Ab[256 * AST];  // [col=gs*8+a][e]
    __shared__ __align__(16) unsigned short Bb[16 * AST];   // [n=b][e]
    int gd = blockIdx.x, c = blockIdx.y;
    int t = threadIdx.x;
    int wave = t >> 6, lane = t & 63;
    int q = lane >> 4, lr = lane & 15;
    int n0g = (gd * N_ + 31) >> 5;
    int n1g = ((gd + 1) * N_ + 31) >> 5;
    int len = n1g - n0g;
    int na = n0g + (len * c) / ACHUNK;
    int nb = n0g + (len * (c + 1)) / ACHUNK;
    int j0 = rowStart[na], j1 = rowStart[nb];

    // zero all of Bb once (rows 8..15 stay zero forever)
    uint4 z = {0, 0, 0, 0};
    if (t < 144) *(uint4*)&Bb[t * 8] = z;

    f32x4 acc[4] = {};
    int el = t >> 2;   // edge slot 0..63
    int ap = t & 3;    // value-pair 0..3 (a = 2*ap, 2*ap+1)

    for (int jt = j0; jt < j1; jt += 64) {
        __syncthreads();  // protect zero-fill vs previous tile's fragment reads
#pragma unroll
        for (int i = 0; i < 9; i++) {
            int o = (i * 256 + t) * 8;  // covers 256*AST = 18432 u16 exactly
            *(uint4*)&Ab[o] = z;
        }
        if (t < 72) *(uint4*)&Bb[t * 8] = z;  // rows 0..7
        __syncthreads();
        int j = jt + el;
        if (j < j1) {
            int s = csr_src[j], d = csr_dst[j];
            int gs = (s * B_) / N_;
            unsigned sv = *(const unsigned*)(r8b + s * 8 + ap * 2);
            unsigned dv = *(const unsigned*)(r8b + d * 8 + ap * 2);
            int ca = gs * 8 + ap * 2;
            Ab[ca * AST + el] = (unsigned short)sv;
            Ab[(ca + 1) * AST + el] = (unsigned short)(sv >> 16);
            Bb[(ap * 2) * AST + el] = (unsigned short)dv;
            Bb[(ap * 2 + 1) * AST + el] = (unsigned short)(dv >> 16);
        }
        __syncthreads();
        short8 bf0 = *(const short8*)&Bb[lr * AST + q * 8];
        short8 bf1 = *(const short8*)&Bb[lr * AST + 32 + q * 8];
#pragma unroll
        for (int mi = 0; mi < 4; mi++) {
            int col = (wave * 4 + mi) * 16 + lr;
            short8 a0 = *(const short8*)&Ab[col * AST + q * 8];
            short8 a1 = *(const short8*)&Ab[col * AST + 32 + q * 8];
            acc[mi] = __builtin_amdgcn_mfma_f32_16x16x32_bf16(a0, bf0, acc[mi], 0, 0, 0);
            acc[mi] = __builtin_amdgcn_mfma_f32_16x16x32_bf16(a1, bf1, acc[mi], 0, 0, 0);
        }
    }

    // D layout: col(n)=lane&15, row(m)=q*4+reg; adj row = m, adj col-in-block = n (<8)
    float* pb = partAdj + (gd * ACHUNK + c) * 2048;
    if (lr < 8) {
#pragma unroll
        for (int mi = 0; mi < 4; mi++) {
            int mbase = (wave * 4 + mi) * 16 + q * 4;
#pragma unroll
            for (int r = 0; r < 4; r++)
                pb[(mbase + r) * 8 + lr] = acc[mi][r];
        }
    }
}

// ---------------- adj reduce ----------------
__global__ __launch_bounds__(256) void k_adj_red(const float* __restrict__ partAdj,
                                                 float* __restrict__ adj) {
    int o = blockIdx.x * 256 + threadIdx.x;
    if (o >= 256 * 256) return;
    int row = o >> 8, col = o & 255;
    int gd = col >> 3, b = col & 7;
    int li = row * 8 + b;
    float s = 0.f;
#pragma unroll
    for (int c = 0; c < ACHUNK; c++) s += partAdj[(gd * ACHUNK + c) * 2048 + li];
    adj[o] = s;
}

extern "C" void kernel_launch(void* const* d_in, const int* in_sizes, int n_in,
                              void* d_out, int out_size, void* d_ws, size_t ws_size,
                              hipStream_t stream) {
    const float* x = (const float*)d_in[0];
    const int* ei = (const int*)d_in[1];
    const int* batch = (const int*)d_in[2];
    const float* We = (const float*)d_in[3];
    const float* be = (const float*)d_in[4];
    const float* Wp = (const float*)d_in[5];
    const float* bp = (const float*)d_in[6];
    float* out = (float*)d_out;  // [adj 256*256 | h 256*128]

    char* w = (char*)d_ws;
    auto alloc = [&](size_t bytes) -> char* {
        char* p = w;
        w += (bytes + 255) & ~(size_t)255;
        return p;
    };
    unsigned short* xhi = (unsigned short*)alloc((size_t)N_ * 128 * 2);
    unsigned short* xlo = (unsigned short*)alloc((size_t)N_ * 128 * 2);
    unsigned short* nhi = (unsigned short*)alloc((size_t)N_ * 128 * 2);
    unsigned short* nlo = (unsigned short*)alloc((size_t)N_ * 128 * 2);
    unsigned short* WThi = (unsigned short*)alloc((size_t)JTOT * KTOT * 2);
    unsigned short* WTlo = (unsigned short*)alloc((size_t)JTOT * KTOT * 2);
    float* embed = (float*)alloc((size_t)N_ * 128 * 4);
    float* plog = (float*)alloc((size_t)N_ * 256 * 4);
    float* r8 = (float*)alloc((size_t)N_ * 8 * 4);
    unsigned short* r8b = (unsigned short*)alloc((size_t)N_ * 8 * 2);
    float* bias = (float*)alloc(JTOT * 4);
    int* deg = (int*)alloc((size_t)N_ * 4);
    int* rowStart = (int*)alloc((size_t)(N_ + 1) * 4);
    int* rowFill = (int*)alloc((size_t)N_ * 4);
    int* csr_src = (int*)alloc((size_t)E_ * 4);
    int* csr_dst = (int*)alloc((size_t)E_ * 4);
    float* partH = (float*)alloc((size_t)B_ * HCHUNK * 1024 * 4);
    float* partAdj = (float*)alloc((size_t)B_ * ACHUNK * 2048 * 4);

    (void)hipMemsetAsync(deg, 0, (size_t)N_ * 4, stream);

    k_hist<<<(E_ + 255) / 256, 256, 0, stream>>>(ei, deg);
    k_scan<<<1, SCAN_T, 0, stream>>>(deg, rowStart, rowFill);
    k_scatter<<<(E_ + 255) / 256, 256, 0, stream>>>(ei, rowFill, csr_src, csr_dst);
    k_convx<<<(N_ * 128 / 4 + 255) / 256, 256, 0, stream>>>(x, xhi, xlo);
    k_agg<<<(N_ + 3) / 4, 256, 0, stream>>>(x, rowStart, csr_src, nhi, nlo);
    k_prep<<<(JTOT * KTOT + 255) / 256, 256, 0, stream>>>(We, be, Wp, bp, WThi, WTlo, bias);
    dim3 gg((N_ + 127) / 128, JTOT / 128);
    k_gemm<<<gg, 256, 0, stream>>>(xhi, xlo, nhi, nlo, WThi, WTlo, bias, embed, plog);
    k_r<<<(N_ + 3) / 4, 256, 0, stream>>>(plog, batch, r8, r8b);
    dim3 hg(B_, HCHUNK);
    k_h_part<<<hg, 256, 0, stream>>>(embed, r8, partH);
    k_h_red<<<(256 * 128 + 255) / 256, 256, 0, stream>>>(partH, out + 256 * 256);
    dim3 ag(B_, ACHUNK);
    k_adjm<<<ag, 256, 0, stream>>>(rowStart, csr_src, csr_dst, r8b, partAdj);
    k_adj_red<<<(256 * 256 + 255) / 256, 256, 0, stream>>>(partAdj, out);
}

// Round 8
// 366.244 us; speedup vs baseline: 1.9838x; 1.3037x over previous
//
#include <hip/hip_runtime.h>
#include <hip/hip_bf16.h>

#define N_ 50000
#define E_ 800000
#define IN_ 128
#define OUT_ 128
#define ASSIGN_ 256
#define B_ 32
#define KTOT 256     // 2*IN
#define JTOT 384     // OUT + ASSIGN
#define HCHUNK 16
#define ACHUNK 16
#define AST 72       // LDS row stride in u16 (144 B: 16B-aligned, bank-spread)
#define NB_SCAN ((N_ + 255) / 256)   // 196

typedef __attribute__((ext_vector_type(8))) short short8;
typedef __attribute__((ext_vector_type(4))) float f32x4;
typedef __attribute__((ext_vector_type(4))) unsigned short ushort4v;
typedef __attribute__((ext_vector_type(2))) unsigned short ushort2v;

struct HL { unsigned short h, l; };

__device__ inline unsigned short f2bf(float v) {
    union { float f; unsigned u; } a;
    a.f = v;
    unsigned r = a.u + 0x7fff + ((a.u >> 16) & 1);  // RNE
    return (unsigned short)(r >> 16);
}
__device__ inline float bf2f(unsigned short b) {
    union { unsigned u; float f; } a;
    a.u = ((unsigned)b) << 16;
    return a.f;
}
__device__ inline HL split2(float v) {
    HL r;
    r.h = f2bf(v);
    r.l = f2bf(v - bf2f(r.h));
    return r;
}

// ---------------- histogram: deg[dst]++ ----------------
__global__ void k_hist(const int* __restrict__ ei, int* __restrict__ deg) {
    int e = blockIdx.x * 256 + threadIdx.x;
    if (e < E_) atomicAdd(&deg[ei[E_ + e]], 1);
}

// ---------------- multi-block exclusive scan: deg -> rowStart/rowFill ----------------
__global__ __launch_bounds__(256) void k_scan_a(const int* __restrict__ deg,
                                                int* __restrict__ blockSum) {
    __shared__ int sh[256];
    int t = threadIdx.x;
    int i = blockIdx.x * 256 + t;
    sh[t] = (i < N_) ? deg[i] : 0;
    __syncthreads();
    for (int off = 128; off; off >>= 1) {
        if (t < off) sh[t] += sh[t + off];
        __syncthreads();
    }
    if (t == 0) blockSum[blockIdx.x] = sh[0];
}

__global__ __launch_bounds__(256) void k_scan_b(const int* __restrict__ blockSum,
                                                int* __restrict__ blockOff) {
    __shared__ int sh[256];
    int t = threadIdx.x;
    sh[t] = (t < NB_SCAN) ? blockSum[t] : 0;
    __syncthreads();
    for (int off = 1; off < 256; off <<= 1) {
        int x = sh[t];
        int add = (t >= off) ? sh[t - off] : 0;
        __syncthreads();
        sh[t] = x + add;
        __syncthreads();
    }
    if (t < NB_SCAN) blockOff[t] = (t == 0) ? 0 : sh[t - 1];
}

__global__ __launch_bounds__(256) void k_scan_c(const int* __restrict__ deg,
                                                const int* __restrict__ blockOff,
                                                int* __restrict__ rowStart,
                                                int* __restrict__ rowFill) {
    __shared__ int sh[256];
    int t = threadIdx.x;
    int i = blockIdx.x * 256 + t;
    int v = (i < N_) ? deg[i] : 0;
    sh[t] = v;
    __syncthreads();
    for (int off = 1; off < 256; off <<= 1) {
        int x = sh[t];
        int add = (t >= off) ? sh[t - off] : 0;
        __syncthreads();
        sh[t] = x + add;
        __syncthreads();
    }
    int excl = blockOff[blockIdx.x] + ((t == 0) ? 0 : sh[t - 1]);
    if (i < N_) {
        rowStart[i] = excl;
        rowFill[i] = excl;
    }
    if (i == 0) rowStart[N_] = E_;  // total degree == number of edges (constant)
}

// ---------------- scatter edges into CSR-by-dst (src and dst arrays) ----------------
__global__ void k_scatter(const int* __restrict__ ei, int* __restrict__ rowFill,
                          int* __restrict__ csr_src, int* __restrict__ csr_dst) {
    int e = blockIdx.x * 256 + threadIdx.x;
    if (e >= E_) return;
    int s = ei[e], d = ei[E_ + e];
    int p = atomicAdd(&rowFill[d], 1);
    csr_src[p] = s;
    csr_dst[p] = d;
}

// ---------------- neigh mean -> bf16 hi/lo (one wave per node) ------
__global__ __launch_bounds__(256) void k_agg(const float* __restrict__ x,
                                             const int* __restrict__ rowStart,
                                             const int* __restrict__ csr_src,
                                             unsigned short* __restrict__ nhi,
                                             unsigned short* __restrict__ nlo) {
    int node = blockIdx.x * 4 + (threadIdx.x >> 6);
    int lane = threadIdx.x & 63;
    if (node >= N_) return;
    int a = rowStart[node], bnd = rowStart[node + 1];
    float ax = 0.f, ay = 0.f;
    int j = a;
    for (; j + 1 < bnd; j += 2) {
        int s0 = csr_src[j], s1 = csr_src[j + 1];
        float2 v0 = *(const float2*)(x + s0 * 128 + lane * 2);
        float2 v1 = *(const float2*)(x + s1 * 128 + lane * 2);
        ax += v0.x + v1.x;
        ay += v0.y + v1.y;
    }
    if (j < bnd) {
        int s0 = csr_src[j];
        float2 v0 = *(const float2*)(x + s0 * 128 + lane * 2);
        ax += v0.x;
        ay += v0.y;
    }
    float inv = 1.0f / (float)max(bnd - a, 1);
    ax *= inv;
    ay *= inv;
    HL hx = split2(ax), hy = split2(ay);
    ushort2v h, l;
    h.x = hx.h; h.y = hy.h;
    l.x = hx.l; l.y = hy.l;
    *(ushort2v*)(nhi + node * 128 + lane * 2) = h;
    *(ushort2v*)(nlo + node * 128 + lane * 2) = l;
}

// ---------------- x -> bf16 hi/lo ----------------
__global__ __launch_bounds__(256) void k_convx(const float* __restrict__ x,
                                               unsigned short* __restrict__ xhi,
                                               unsigned short* __restrict__ xlo) {
    int i4 = (blockIdx.x * 256 + threadIdx.x) * 4;
    if (i4 >= N_ * 128) return;
    float4 v = *(const float4*)(x + i4);
    HL a = split2(v.x), b = split2(v.y), c = split2(v.z), d = split2(v.w);
    ushort4v h, l;
    h.x = a.h; h.y = b.h; h.z = c.h; h.w = d.h;
    l.x = a.l; l.y = b.l; l.z = c.l; l.w = d.l;
    *(ushort4v*)(xhi + i4) = h;
    *(ushort4v*)(xlo + i4) = l;
}

// ---------------- W transposed -> bf16 hi/lo WT[j][k], plus bias ----------------
__global__ void k_prep(const float* __restrict__ We, const float* __restrict__ be,
                       const float* __restrict__ Wp, const float* __restrict__ bp,
                       unsigned short* __restrict__ WThi, unsigned short* __restrict__ WTlo,
                       float* __restrict__ bias) {
    int idx = blockIdx.x * 256 + threadIdx.x;
    if (idx < JTOT * KTOT) {
        int j = idx / KTOT, k = idx - j * KTOT;
        float v = (j < 128) ? We[k * 128 + j] : Wp[k * 256 + (j - 128)];
        HL s = split2(v);
        WThi[idx] = s.h;
        WTlo[idx] = s.l;
    }
    if (idx < JTOT) bias[idx] = (idx < 128) ? be[idx] : bp[idx - 128];
}

// ---------------- MFMA GEMM (bf16x3 split): [x|neigh] (N x 256) @ W (256 x 384) ----------------
#define LDA 40
__global__ __launch_bounds__(256) void k_gemm(const unsigned short* __restrict__ xhi,
                                              const unsigned short* __restrict__ xlo,
                                              const unsigned short* __restrict__ nhi,
                                              const unsigned short* __restrict__ nlo,
                                              const unsigned short* __restrict__ WThi,
                                              const unsigned short* __restrict__ WTlo,
                                              const float* __restrict__ bias,
                                              float* __restrict__ embed,
                                              float* __restrict__ plog) {
    __shared__ unsigned short Ah[128][LDA], Al[128][LDA], Bh[128][LDA], Bl[128][LDA];
    int t = threadIdx.x;
    int wave = t >> 6, lane = t & 63;
    int wm = wave >> 1, wn = wave & 1;
    int q = lane >> 4, lr = lane & 15;
    int row0 = blockIdx.x * 128;
    int col0 = blockIdx.y * 128;

    f32x4 acc[4][4] = {};

    int sm = t >> 1;
    int kc = (t & 1) * 16;

    for (int kt = 0; kt < KTOT; kt += 32) {
        const unsigned short* Ah_src = (kt < 128) ? xhi : nhi;
        const unsigned short* Al_src = (kt < 128) ? xlo : nlo;
        int kb = (kt & 127) + kc;
        int node = row0 + sm;
        short8 vh0 = {}, vh1 = {}, vl0 = {}, vl1 = {};
        if (node < N_) {
            const short8* ph = (const short8*)(Ah_src + (size_t)node * 128 + kb);
            const short8* pl = (const short8*)(Al_src + (size_t)node * 128 + kb);
            vh0 = ph[0]; vh1 = ph[1];
            vl0 = pl[0]; vl1 = pl[1];
        }
        *(short8*)&Ah[sm][kc] = vh0;
        *(short8*)&Ah[sm][kc + 8] = vh1;
        *(short8*)&Al[sm][kc] = vl0;
        *(short8*)&Al[sm][kc + 8] = vl1;
        {
            int j = col0 + sm;
            const short8* ph = (const short8*)(WThi + (size_t)j * 256 + kt + kc);
            const short8* pl = (const short8*)(WTlo + (size_t)j * 256 + kt + kc);
            short8 wh0 = ph[0], wh1 = ph[1];
            short8 wl0 = pl[0], wl1 = pl[1];
            *(short8*)&Bh[sm][kc] = wh0;
            *(short8*)&Bh[sm][kc + 8] = wh1;
            *(short8*)&Bl[sm][kc] = wl0;
            *(short8*)&Bl[sm][kc + 8] = wl1;
        }
        __syncthreads();

        short8 afh[4], afl[4];
#pragma unroll
        for (int mi = 0; mi < 4; mi++) {
            int r = wm * 64 + mi * 16 + lr;
            afh[mi] = *(const short8*)&Ah[r][q * 8];
            afl[mi] = *(const short8*)&Al[r][q * 8];
        }
#pragma unroll
        for (int ni = 0; ni < 4; ni++) {
            int r = wn * 64 + ni * 16 + lr;
            short8 bfh = *(const short8*)&Bh[r][q * 8];
            short8 bfl = *(const short8*)&Bl[r][q * 8];
#pragma unroll
            for (int mi = 0; mi < 4; mi++) {
                acc[mi][ni] = __builtin_amdgcn_mfma_f32_16x16x32_bf16(afh[mi], bfh, acc[mi][ni], 0, 0, 0);
                acc[mi][ni] = __builtin_amdgcn_mfma_f32_16x16x32_bf16(afh[mi], bfl, acc[mi][ni], 0, 0, 0);
                acc[mi][ni] = __builtin_amdgcn_mfma_f32_16x16x32_bf16(afl[mi], bfh, acc[mi][ni], 0, 0, 0);
            }
        }
        __syncthreads();
    }

#pragma unroll
    for (int ni = 0; ni < 4; ni++) {
        int col = col0 + wn * 64 + ni * 16 + lr;
        float bj = bias[col];
#pragma unroll
        for (int mi = 0; mi < 4; mi++) {
            int rbase = row0 + wm * 64 + mi * 16 + q * 4;
#pragma unroll
            for (int r = 0; r < 4; r++) {
                int row = rbase + r;
                if (row >= N_) continue;
                float v = acc[mi][ni][r] + bj;
                if (col < 128)
                    embed[(size_t)row * 128 + col] = v;
                else
                    plog[(size_t)row * 256 + (col - 128)] = v;
            }
        }
    }
}

// ---------------- double softmax -> compact r8[N][8] (fp32 + bf16 copy) ----------------
__global__ __launch_bounds__(256) void k_r(const float* __restrict__ plog,
                                           const int* __restrict__ batch,
                                           float* __restrict__ r8,
                                           unsigned short* __restrict__ r8b) {
    int node = blockIdx.x * 4 + (threadIdx.x >> 6);
    int lane = threadIdx.x & 63;
    if (node >= N_) return;
    float4 p = *(const float4*)(plog + node * 256 + lane * 4);
    float m = fmaxf(fmaxf(p.x, p.y), fmaxf(p.z, p.w));
    for (int off = 32; off; off >>= 1) m = fmaxf(m, __shfl_xor(m, off, 64));
    float s = expf(p.x - m) + expf(p.y - m) + expf(p.z - m) + expf(p.w - m);
    for (int off = 32; off; off >>= 1) s += __shfl_xor(s, off, 64);
    int g = batch[node];
    float v = 0.f;
    if (lane < 8) v = expf(plog[node * 256 + g * 8 + lane] - m) / s;
    float M2 = v;
    for (int off = 4; off; off >>= 1) M2 = fmaxf(M2, __shfl_xor(M2, off, 64));
    float e = expf(v - M2);
    float Sg = e;
    for (int off = 4; off; off >>= 1) Sg += __shfl_xor(Sg, off, 64);
    float D2 = Sg + 248.0f * expf(-M2);
    float r = e / (Sg + 1e-13f * D2);
    if (lane < 8) {
        r8[node * 8 + lane] = r;
        r8b[node * 8 + lane] = f2bf(r);
    }
}

// ---------------- h partials ----------------
__global__ __launch_bounds__(256) void k_h_part(const float* __restrict__ embed,
                                                const float* __restrict__ r8,
                                                float* __restrict__ partH) {
    int g = blockIdx.x;
    int c = blockIdx.y;
    int t = threadIdx.x;
    int o = t & 127, half = t >> 7;
    int n0g = (g * N_ + 31) >> 5;
    int n1g = ((g + 1) * N_ + 31) >> 5;
    int len = n1g - n0g;
    int a = n0g + (len * c) / HCHUNK;
    int b = n0g + (len * (c + 1)) / HCHUNK;
    float a0 = 0.f, a1 = 0.f, a2 = 0.f, a3 = 0.f;
#pragma unroll 4
    for (int n = a; n < b; n++) {
        float e = embed[n * 128 + o];
        const float* rr = r8 + n * 8 + half;
        a0 += rr[0] * e;
        a1 += rr[2] * e;
        a2 += rr[4] * e;
        a3 += rr[6] * e;
    }
    float* pb = partH + (g * HCHUNK + c) * 1024;
    pb[(half + 0) * 128 + o] = a0;
    pb[(half + 2) * 128 + o] = a1;
    pb[(half + 4) * 128 + o] = a2;
    pb[(half + 6) * 128 + o] = a3;
}

// ---------------- h reduce ----------------
__global__ __launch_bounds__(256) void k_h_red(const float* __restrict__ partH,
                                               float* __restrict__ out_h) {
    int idx = blockIdx.x * 256 + threadIdx.x;
    if (idx >= 256 * 128) return;
    int g = idx >> 10;
    int local = idx & 1023;
    float s = 0.f;
#pragma unroll
    for (int c = 0; c < HCHUNK; c++) s += partH[(g * HCHUNK + c) * 1024 + local];
    out_h[idx] = s;
}

// ---------------- adj via MFMA over edge tiles ----------------
__global__ __launch_bounds__(256) void k_adjm(const int* __restrict__ rowStart,
                                              const int* __restrict__ csr_src,
                                              const int* __restrict__ csr_dst,
                                              const unsigned short* __restrict__ r8b,
                                              float* __restrict__ partAdj) {
    __shared__ __align__(16) unsigned short Ab[256 * AST];  // [col=gs*8+a][e]
    __shared__ __align__(16) unsigned short Bb[16 * AST];   // [n=b][e]
    int gd = blockIdx.x, c = blockIdx.y;
    int t = threadIdx.x;
    int wave = t >> 6, lane = t & 63;
    int q = lane >> 4, lr = lane & 15;
    int n0g = (gd * N_ + 31) >> 5;
    int n1g = ((gd + 1) * N_ + 31) >> 5;
    int len = n1g - n0g;
    int na = n0g + (len * c) / ACHUNK;
    int nb = n0g + (len * (c + 1)) / ACHUNK;
    int j0 = rowStart[na], j1 = rowStart[nb];

    uint4 z = {0, 0, 0, 0};
    if (t < 144) *(uint4*)&Bb[t * 8] = z;

    f32x4 acc[4] = {};
    int el = t >> 2;   // edge slot 0..63
    int ap = t & 3;    // value-pair 0..3

    for (int jt = j0; jt < j1; jt += 64) {
        __syncthreads();
#pragma unroll
        for (int i = 0; i < 9; i++) {
            int o = (i * 256 + t) * 8;
            *(uint4*)&Ab[o] = z;
        }
        if (t < 72) *(uint4*)&Bb[t * 8] = z;
        __syncthreads();
        int j = jt + el;
        if (j < j1) {
            int s = csr_src[j], d = csr_dst[j];
            int gs = (s * B_) / N_;
            unsigned sv = *(const unsigned*)(r8b + s * 8 + ap * 2);
            unsigned dv = *(const unsigned*)(r8b + d * 8 + ap * 2);
            int ca = gs * 8 + ap * 2;
            Ab[ca * AST + el] = (unsigned short)sv;
            Ab[(ca + 1) * AST + el] = (unsigned short)(sv >> 16);
            Bb[(ap * 2) * AST + el] = (unsigned short)dv;
            Bb[(ap * 2 + 1) * AST + el] = (unsigned short)(dv >> 16);
        }
        __syncthreads();
        short8 bf0 = *(const short8*)&Bb[lr * AST + q * 8];
        short8 bf1 = *(const short8*)&Bb[lr * AST + 32 + q * 8];
#pragma unroll
        for (int mi = 0; mi < 4; mi++) {
            int col = (wave * 4 + mi) * 16 + lr;
            short8 a0 = *(const short8*)&Ab[col * AST + q * 8];
            short8 a1 = *(const short8*)&Ab[col * AST + 32 + q * 8];
            acc[mi] = __builtin_amdgcn_mfma_f32_16x16x32_bf16(a0, bf0, acc[mi], 0, 0, 0);
            acc[mi] = __builtin_amdgcn_mfma_f32_16x16x32_bf16(a1, bf1, acc[mi], 0, 0, 0);
        }
    }

    float* pb = partAdj + (gd * ACHUNK + c) * 2048;
    if (lr < 8) {
#pragma unroll
        for (int mi = 0; mi < 4; mi++) {
            int mbase = (wave * 4 + mi) * 16 + q * 4;
#pragma unroll
            for (int r = 0; r < 4; r++)
                pb[(mbase + r) * 8 + lr] = acc[mi][r];
        }
    }
}

// ---------------- adj reduce ----------------
__global__ __launch_bounds__(256) void k_adj_red(const float* __restrict__ partAdj,
                                                 float* __restrict__ adj) {
    int o = blockIdx.x * 256 + threadIdx.x;
    if (o >= 256 * 256) return;
    int row = o >> 8, col = o & 255;
    int gd = col >> 3, b = col & 7;
    int li = row * 8 + b;
    float s = 0.f;
#pragma unroll
    for (int c = 0; c < ACHUNK; c++) s += partAdj[(gd * ACHUNK + c) * 2048 + li];
    adj[o] = s;
}

extern "C" void kernel_launch(void* const* d_in, const int* in_sizes, int n_in,
                              void* d_out, int out_size, void* d_ws, size_t ws_size,
                              hipStream_t stream) {
    const float* x = (const float*)d_in[0];
    const int* ei = (const int*)d_in[1];
    const int* batch = (const int*)d_in[2];
    const float* We = (const float*)d_in[3];
    const float* be = (const float*)d_in[4];
    const float* Wp = (const float*)d_in[5];
    const float* bp = (const float*)d_in[6];
    float* out = (float*)d_out;  // [adj 256*256 | h 256*128]

    char* w = (char*)d_ws;
    auto alloc = [&](size_t bytes) -> char* {
        char* p = w;
        w += (bytes + 255) & ~(size_t)255;
        return p;
    };
    unsigned short* xhi = (unsigned short*)alloc((size_t)N_ * 128 * 2);
    unsigned short* xlo = (unsigned short*)alloc((size_t)N_ * 128 * 2);
    unsigned short* nhi = (unsigned short*)alloc((size_t)N_ * 128 * 2);
    unsigned short* nlo = (unsigned short*)alloc((size_t)N_ * 128 * 2);
    unsigned short* WThi = (unsigned short*)alloc((size_t)JTOT * KTOT * 2);
    unsigned short* WTlo = (unsigned short*)alloc((size_t)JTOT * KTOT * 2);
    float* embed = (float*)alloc((size_t)N_ * 128 * 4);
    float* plog = (float*)alloc((size_t)N_ * 256 * 4);
    float* r8 = (float*)alloc((size_t)N_ * 8 * 4);
    unsigned short* r8b = (unsigned short*)alloc((size_t)N_ * 8 * 2);
    float* bias = (float*)alloc(JTOT * 4);
    int* deg = (int*)alloc((size_t)N_ * 4);
    int* rowStart = (int*)alloc((size_t)(N_ + 1) * 4);
    int* rowFill = (int*)alloc((size_t)N_ * 4);
    int* csr_src = (int*)alloc((size_t)E_ * 4);
    int* csr_dst = (int*)alloc((size_t)E_ * 4);
    int* blockSum = (int*)alloc(NB_SCAN * 4);
    int* blockOff = (int*)alloc(NB_SCAN * 4);
    float* partH = (float*)alloc((size_t)B_ * HCHUNK * 1024 * 4);
    float* partAdj = (float*)alloc((size_t)B_ * ACHUNK * 2048 * 4);

    (void)hipMemsetAsync(deg, 0, (size_t)N_ * 4, stream);

    k_hist<<<(E_ + 255) / 256, 256, 0, stream>>>(ei, deg);
    k_scan_a<<<NB_SCAN, 256, 0, stream>>>(deg, blockSum);
    k_scan_b<<<1, 256, 0, stream>>>(blockSum, blockOff);
    k_scan_c<<<NB_SCAN, 256, 0, stream>>>(deg, blockOff, rowStart, rowFill);
    k_scatter<<<(E_ + 255) / 256, 256, 0, stream>>>(ei, rowFill, csr_src, csr_dst);
    k_convx<<<(N_ * 128 / 4 + 255) / 256, 256, 0, stream>>>(x, xhi, xlo);
    k_agg<<<(N_ + 3) / 4, 256, 0, stream>>>(x, rowStart, csr_src, nhi, nlo);
    k_prep<<<(JTOT * KTOT + 255) / 256, 256, 0, stream>>>(We, be, Wp, bp, WThi, WTlo, bias);
    dim3 gg((N_ + 127) / 128, JTOT / 128);
    k_gemm<<<gg, 256, 0, stream>>>(xhi, xlo, nhi, nlo, WThi, WTlo, bias, embed, plog);
    k_r<<<(N_ + 3) / 4, 256, 0, stream>>>(plog, batch, r8, r8b);
    dim3 hg(B_, HCHUNK);
    k_h_part<<<hg, 256, 0, stream>>>(embed, r8, partH);
    k_h_red<<<(256 * 128 + 255) / 256, 256, 0, stream>>>(partH, out + 256 * 256);
    dim3 ag(B_, ACHUNK);
    k_adjm<<<ag, 256, 0, stream>>>(rowStart, csr_src, csr_dst, r8b, partAdj);
    k_adj_red<<<(256 * 256 + 255) / 256, 256, 0, stream>>>(partAdj, out);
}

// Round 9
// 363.367 us; speedup vs baseline: 1.9995x; 1.0079x over previous
//
#include <hip/hip_runtime.h>
#include <hip/hip_bf16.h>

#define N_ 50000
#define E_ 800000
#define IN_ 128
#define OUT_ 128
#define ASSIGN_ 256
#define B_ 32
#define KTOT 256     // 2*IN
#define JTOT 384     // OUT + ASSIGN
#define HCHUNK 16
#define ACHUNK 16
#define AST 72       // k_adjm LDS row stride in u16
#define NB_SCAN ((N_ + 255) / 256)   // 196

typedef __attribute__((ext_vector_type(8))) short short8;
typedef __attribute__((ext_vector_type(4))) float f32x4;
typedef __attribute__((ext_vector_type(4))) unsigned short ushort4v;
typedef __attribute__((ext_vector_type(2))) unsigned short ushort2v;
typedef unsigned short u16;

struct HL { unsigned short h, l; };

__device__ inline unsigned short f2bf(float v) {
    union { float f; unsigned u; } a;
    a.f = v;
    unsigned r = a.u + 0x7fff + ((a.u >> 16) & 1);  // RNE
    return (unsigned short)(r >> 16);
}
__device__ inline float bf2f(unsigned short b) {
    union { unsigned u; float f; } a;
    a.u = ((unsigned)b) << 16;
    return a.f;
}
__device__ inline HL split2(float v) {
    HL r;
    r.h = f2bf(v);
    r.l = f2bf(v - bf2f(r.h));
    return r;
}

// async global->LDS, 16 B per lane; LDS dest = wave-uniform base + lane*16
#define GLOAD16(gp, lp)                                                  \
    __builtin_amdgcn_global_load_lds(                                    \
        (__attribute__((address_space(1))) void*)(gp),                   \
        (__attribute__((address_space(3))) void*)(lp), 16, 0, 0)

// ---------------- histogram: deg[dst]++ ----------------
__global__ void k_hist(const int* __restrict__ ei, int* __restrict__ deg) {
    int e = blockIdx.x * 256 + threadIdx.x;
    if (e < E_) atomicAdd(&deg[ei[E_ + e]], 1);
}

// ---------------- multi-block exclusive scan: deg -> rowStart/rowFill ----------------
__global__ __launch_bounds__(256) void k_scan_a(const int* __restrict__ deg,
                                                int* __restrict__ blockSum) {
    __shared__ int sh[256];
    int t = threadIdx.x;
    int i = blockIdx.x * 256 + t;
    sh[t] = (i < N_) ? deg[i] : 0;
    __syncthreads();
    for (int off = 128; off; off >>= 1) {
        if (t < off) sh[t] += sh[t + off];
        __syncthreads();
    }
    if (t == 0) blockSum[blockIdx.x] = sh[0];
}

__global__ __launch_bounds__(256) void k_scan_b(const int* __restrict__ blockSum,
                                                int* __restrict__ blockOff) {
    __shared__ int sh[256];
    int t = threadIdx.x;
    sh[t] = (t < NB_SCAN) ? blockSum[t] : 0;
    __syncthreads();
    for (int off = 1; off < 256; off <<= 1) {
        int x = sh[t];
        int add = (t >= off) ? sh[t - off] : 0;
        __syncthreads();
        sh[t] = x + add;
        __syncthreads();
    }
    if (t < NB_SCAN) blockOff[t] = (t == 0) ? 0 : sh[t - 1];
}

__global__ __launch_bounds__(256) void k_scan_c(const int* __restrict__ deg,
                                                const int* __restrict__ blockOff,
                                                int* __restrict__ rowStart,
                                                int* __restrict__ rowFill) {
    __shared__ int sh[256];
    int t = threadIdx.x;
    int i = blockIdx.x * 256 + t;
    int v = (i < N_) ? deg[i] : 0;
    sh[t] = v;
    __syncthreads();
    for (int off = 1; off < 256; off <<= 1) {
        int x = sh[t];
        int add = (t >= off) ? sh[t - off] : 0;
        __syncthreads();
        sh[t] = x + add;
        __syncthreads();
    }
    int excl = blockOff[blockIdx.x] + ((t == 0) ? 0 : sh[t - 1]);
    if (i < N_) {
        rowStart[i] = excl;
        rowFill[i] = excl;
    }
    if (i == 0) rowStart[N_] = E_;
}

// ---------------- scatter edges into CSR-by-dst, packed (src,dst) ----------------
__global__ void k_scatter(const int* __restrict__ ei, int* __restrict__ rowFill,
                          int2* __restrict__ csr) {
    int e = blockIdx.x * 256 + threadIdx.x;
    if (e >= E_) return;
    int s = ei[e], d = ei[E_ + e];
    int p = atomicAdd(&rowFill[d], 1);
    csr[p] = make_int2(s, d);
}

// ---------------- neigh mean -> bf16 hi/lo (one wave per node) ------
__global__ __launch_bounds__(256) void k_agg(const float* __restrict__ x,
                                             const int* __restrict__ rowStart,
                                             const int2* __restrict__ csr,
                                             unsigned short* __restrict__ nhi,
                                             unsigned short* __restrict__ nlo) {
    int node = blockIdx.x * 4 + (threadIdx.x >> 6);
    int lane = threadIdx.x & 63;
    if (node >= N_) return;
    int a = rowStart[node], bnd = rowStart[node + 1];
    float ax = 0.f, ay = 0.f;
    int j = a;
    for (; j + 1 < bnd; j += 2) {
        int s0 = csr[j].x, s1 = csr[j + 1].x;
        float2 v0 = *(const float2*)(x + s0 * 128 + lane * 2);
        float2 v1 = *(const float2*)(x + s1 * 128 + lane * 2);
        ax += v0.x + v1.x;
        ay += v0.y + v1.y;
    }
    if (j < bnd) {
        int s0 = csr[j].x;
        float2 v0 = *(const float2*)(x + s0 * 128 + lane * 2);
        ax += v0.x;
        ay += v0.y;
    }
    float inv = 1.0f / (float)max(bnd - a, 1);
    ax *= inv;
    ay *= inv;
    HL hx = split2(ax), hy = split2(ay);
    ushort2v h, l;
    h.x = hx.h; h.y = hy.h;
    l.x = hx.l; l.y = hy.l;
    *(ushort2v*)(nhi + node * 128 + lane * 2) = h;
    *(ushort2v*)(nlo + node * 128 + lane * 2) = l;
}

// ---------------- x -> bf16 hi/lo ----------------
__global__ __launch_bounds__(256) void k_convx(const float* __restrict__ x,
                                               unsigned short* __restrict__ xhi,
                                               unsigned short* __restrict__ xlo) {
    int i4 = (blockIdx.x * 256 + threadIdx.x) * 4;
    if (i4 >= N_ * 128) return;
    float4 v = *(const float4*)(x + i4);
    HL a = split2(v.x), b = split2(v.y), c = split2(v.z), d = split2(v.w);
    ushort4v h, l;
    h.x = a.h; h.y = b.h; h.z = c.h; h.w = d.h;
    l.x = a.l; l.y = b.l; l.z = c.l; l.w = d.l;
    *(ushort4v*)(xhi + i4) = h;
    *(ushort4v*)(xlo + i4) = l;
}

// ---------------- W transposed -> bf16 hi/lo WT[j][k], plus bias ----------------
__global__ void k_prep(const float* __restrict__ We, const float* __restrict__ be,
                       const float* __restrict__ Wp, const float* __restrict__ bp,
                       unsigned short* __restrict__ WThi, unsigned short* __restrict__ WTlo,
                       float* __restrict__ bias) {
    int idx = blockIdx.x * 256 + threadIdx.x;
    if (idx < JTOT * KTOT) {
        int j = idx / KTOT, k = idx - j * KTOT;
        float v = (j < 128) ? We[k * 128 + j] : Wp[k * 256 + (j - 128)];
        HL s = split2(v);
        WThi[idx] = s.h;
        WTlo[idx] = s.l;
    }
    if (idx < JTOT) bias[idx] = (idx < 128) ? be[idx] : bp[idx - 128];
}

// ---------------- MFMA GEMM (bf16x3 split), m97-style async staging ----------------
// block tile 128x128, 4 waves (2x2), wave tile 64x64; BK=32; LDS unpadded [128][32]
__global__ __launch_bounds__(256) void k_gemm(const unsigned short* __restrict__ xhi,
                                              const unsigned short* __restrict__ xlo,
                                              const unsigned short* __restrict__ nhi,
                                              const unsigned short* __restrict__ nlo,
                                              const unsigned short* __restrict__ WThi,
                                              const unsigned short* __restrict__ WTlo,
                                              const float* __restrict__ bias,
                                              float* __restrict__ embed,
                                              float* __restrict__ plog) {
    __shared__ u16 Ah[128][32], Al[128][32], Bh[128][32], Bl[128][32];  // 32 KB
    int t = threadIdx.x;
    int wave = t >> 6, lane = t & 63;
    int wm = wave >> 1, wn = wave & 1;
    int q = lane >> 4, lr = lane & 15;
    int row0 = blockIdx.x * 128;
    int col0 = blockIdx.y * 128;

    f32x4 acc[4][4] = {};

    // DMA lane mapping: lane = rowInGroup*4 + kquad; 16 rows (1 KB) per instr
    int row16 = lane >> 2;  // 0..15
    int kq8 = (lane & 3) * 8;

    for (int kt = 0; kt < KTOT; kt += 32) {
        const u16* Ah_src = (kt < 128) ? xhi : nhi;
        const u16* Al_src = (kt < 128) ? xlo : nlo;
        int kb = (kt & 127) + kq8;
#pragma unroll
        for (int i = 0; i < 2; i++) {
            int r = wave * 32 + i * 16 + row16;          // per-lane source row
            int rb = wave * 32 + i * 16;                 // wave-uniform LDS base row
            // A rows beyond N_ read into adjacent ws allocations (valid mem);
            // their C rows are discarded in the guarded epilogue.
            GLOAD16(Ah_src + (size_t)(row0 + r) * 128 + kb, &Ah[rb][0]);
            GLOAD16(Al_src + (size_t)(row0 + r) * 128 + kb, &Al[rb][0]);
            GLOAD16(WThi + (size_t)(col0 + r) * 256 + kt + kq8, &Bh[rb][0]);
            GLOAD16(WTlo + (size_t)(col0 + r) * 256 + kt + kq8, &Bl[rb][0]);
        }
        __syncthreads();  // drains vmcnt (DMA) + orders all waves

        short8 afh[4], afl[4];
#pragma unroll
        for (int mi = 0; mi < 4; mi++) {
            int r = wm * 64 + mi * 16 + lr;
            afh[mi] = *(const short8*)&Ah[r][q * 8];
            afl[mi] = *(const short8*)&Al[r][q * 8];
        }
#pragma unroll
        for (int ni = 0; ni < 4; ni++) {
            int r = wn * 64 + ni * 16 + lr;
            short8 bfh = *(const short8*)&Bh[r][q * 8];
            short8 bfl = *(const short8*)&Bl[r][q * 8];
#pragma unroll
            for (int mi = 0; mi < 4; mi++) {
                acc[mi][ni] = __builtin_amdgcn_mfma_f32_16x16x32_bf16(afh[mi], bfh, acc[mi][ni], 0, 0, 0);
                acc[mi][ni] = __builtin_amdgcn_mfma_f32_16x16x32_bf16(afh[mi], bfl, acc[mi][ni], 0, 0, 0);
                acc[mi][ni] = __builtin_amdgcn_mfma_f32_16x16x32_bf16(afl[mi], bfh, acc[mi][ni], 0, 0, 0);
            }
        }
        __syncthreads();  // protect LDS before next K-step's DMA overwrite
    }

    // epilogue: C/D layout col=lane&15, row=(lane>>4)*4+reg
#pragma unroll
    for (int ni = 0; ni < 4; ni++) {
        int col = col0 + wn * 64 + ni * 16 + lr;
        float bj = bias[col];
#pragma unroll
        for (int mi = 0; mi < 4; mi++) {
            int rbase = row0 + wm * 64 + mi * 16 + q * 4;
#pragma unroll
            for (int r = 0; r < 4; r++) {
                int row = rbase + r;
                if (row >= N_) continue;
                float v = acc[mi][ni][r] + bj;
                if (col < 128)
                    embed[(size_t)row * 128 + col] = v;
                else
                    plog[(size_t)row * 256 + (col - 128)] = v;
            }
        }
    }
}

// ---------------- double softmax -> compact r8[N][8] (fp32 + bf16 copy) ----------------
__global__ __launch_bounds__(256) void k_r(const float* __restrict__ plog,
                                           const int* __restrict__ batch,
                                           float* __restrict__ r8,
                                           unsigned short* __restrict__ r8b) {
    int node = blockIdx.x * 4 + (threadIdx.x >> 6);
    int lane = threadIdx.x & 63;
    if (node >= N_) return;
    float4 p = *(const float4*)(plog + node * 256 + lane * 4);
    float m = fmaxf(fmaxf(p.x, p.y), fmaxf(p.z, p.w));
    for (int off = 32; off; off >>= 1) m = fmaxf(m, __shfl_xor(m, off, 64));
    float s = expf(p.x - m) + expf(p.y - m) + expf(p.z - m) + expf(p.w - m);
    for (int off = 32; off; off >>= 1) s += __shfl_xor(s, off, 64);
    int g = batch[node];
    float v = 0.f;
    if (lane < 8) v = expf(plog[node * 256 + g * 8 + lane] - m) / s;
    float M2 = v;
    for (int off = 4; off; off >>= 1) M2 = fmaxf(M2, __shfl_xor(M2, off, 64));
    float e = expf(v - M2);
    float Sg = e;
    for (int off = 4; off; off >>= 1) Sg += __shfl_xor(Sg, off, 64);
    float D2 = Sg + 248.0f * expf(-M2);
    float r = e / (Sg + 1e-13f * D2);
    if (lane < 8) {
        r8[node * 8 + lane] = r;
        r8b[node * 8 + lane] = f2bf(r);
    }
}

// ---------------- h partials ----------------
__global__ __launch_bounds__(256) void k_h_part(const float* __restrict__ embed,
                                                const float* __restrict__ r8,
                                                float* __restrict__ partH) {
    int g = blockIdx.x;
    int c = blockIdx.y;
    int t = threadIdx.x;
    int o = t & 127, half = t >> 7;
    int n0g = (g * N_ + 31) >> 5;
    int n1g = ((g + 1) * N_ + 31) >> 5;
    int len = n1g - n0g;
    int a = n0g + (len * c) / HCHUNK;
    int b = n0g + (len * (c + 1)) / HCHUNK;
    float a0 = 0.f, a1 = 0.f, a2 = 0.f, a3 = 0.f;
#pragma unroll 4
    for (int n = a; n < b; n++) {
        float e = embed[n * 128 + o];
        const float* rr = r8 + n * 8 + half;
        a0 += rr[0] * e;
        a1 += rr[2] * e;
        a2 += rr[4] * e;
        a3 += rr[6] * e;
    }
    float* pb = partH + (g * HCHUNK + c) * 1024;
    pb[(half + 0) * 128 + o] = a0;
    pb[(half + 2) * 128 + o] = a1;
    pb[(half + 4) * 128 + o] = a2;
    pb[(half + 6) * 128 + o] = a3;
}

// ---------------- h reduce ----------------
__global__ __launch_bounds__(256) void k_h_red(const float* __restrict__ partH,
                                               float* __restrict__ out_h) {
    int idx = blockIdx.x * 256 + threadIdx.x;
    if (idx >= 256 * 128) return;
    int g = idx >> 10;
    int local = idx & 1023;
    float s = 0.f;
#pragma unroll
    for (int c = 0; c < HCHUNK; c++) s += partH[(g * HCHUNK + c) * 1024 + local];
    out_h[idx] = s;
}

// ---------------- adj via MFMA over edge tiles ----------------
__global__ __launch_bounds__(256) void k_adjm(const int* __restrict__ rowStart,
                                              const int2* __restrict__ csr,
                                              const unsigned short* __restrict__ r8b,
                                              float* __restrict__ partAdj) {
    __shared__ __align__(16) unsigned short Ab[256 * AST];  // [col=gs*8+a][e]
    __shared__ __align__(16) unsigned short Bb[16 * AST];   // [n=b][e]
    int gd = blockIdx.x, c = blockIdx.y;
    int t = threadIdx.x;
    int wave = t >> 6, lane = t & 63;
    int q = lane >> 4, lr = lane & 15;
    int n0g = (gd * N_ + 31) >> 5;
    int n1g = ((gd + 1) * N_ + 31) >> 5;
    int len = n1g - n0g;
    int na = n0g + (len * c) / ACHUNK;
    int nb = n0g + (len * (c + 1)) / ACHUNK;
    int j0 = rowStart[na], j1 = rowStart[nb];

    uint4 z = {0, 0, 0, 0};
    if (t < 144) *(uint4*)&Bb[t * 8] = z;

    f32x4 acc[4] = {};
    int el = t >> 2;   // edge slot 0..63
    int ap = t & 3;    // value-pair 0..3

    for (int jt = j0; jt < j1; jt += 64) {
        __syncthreads();
#pragma unroll
        for (int i = 0; i < 9; i++) {
            int o = (i * 256 + t) * 8;
            *(uint4*)&Ab[o] = z;
        }
        if (t < 72) *(uint4*)&Bb[t * 8] = z;
        __syncthreads();
        int j = jt + el;
        if (j < j1) {
            int2 sd = csr[j];
            int s = sd.x, d = sd.y;
            int gs = (s * B_) / N_;
            unsigned sv = *(const unsigned*)(r8b + s * 8 + ap * 2);
            unsigned dv = *(const unsigned*)(r8b + d * 8 + ap * 2);
            int ca = gs * 8 + ap * 2;
            Ab[ca * AST + el] = (unsigned short)sv;
            Ab[(ca + 1) * AST + el] = (unsigned short)(sv >> 16);
            Bb[(ap * 2) * AST + el] = (unsigned short)dv;
            Bb[(ap * 2 + 1) * AST + el] = (unsigned short)(dv >> 16);
        }
        __syncthreads();
        short8 bf0 = *(const short8*)&Bb[lr * AST + q * 8];
        short8 bf1 = *(const short8*)&Bb[lr * AST + 32 + q * 8];
#pragma unroll
        for (int mi = 0; mi < 4; mi++) {
            int col = (wave * 4 + mi) * 16 + lr;
            short8 a0 = *(const short8*)&Ab[col * AST + q * 8];
            short8 a1 = *(const short8*)&Ab[col * AST + 32 + q * 8];
            acc[mi] = __builtin_amdgcn_mfma_f32_16x16x32_bf16(a0, bf0, acc[mi], 0, 0, 0);
            acc[mi] = __builtin_amdgcn_mfma_f32_16x16x32_bf16(a1, bf1, acc[mi], 0, 0, 0);
        }
    }

    float* pb = partAdj + (gd * ACHUNK + c) * 2048;
    if (lr < 8) {
#pragma unroll
        for (int mi = 0; mi < 4; mi++) {
            int mbase = (wave * 4 + mi) * 16 + q * 4;
#pragma unroll
            for (int r = 0; r < 4; r++)
                pb[(mbase + r) * 8 + lr] = acc[mi][r];
        }
    }
}

// ---------------- adj reduce ----------------
__global__ __launch_bounds__(256) void k_adj_red(const float* __restrict__ partAdj,
                                                 float* __restrict__ adj) {
    int o = blockIdx.x * 256 + threadIdx.x;
    if (o >= 256 * 256) return;
    int row = o >> 8, col = o & 255;
    int gd = col >> 3, b = col & 7;
    int li = row * 8 + b;
    float s = 0.f;
#pragma unroll
    for (int c = 0; c < ACHUNK; c++) s += partAdj[(gd * ACHUNK + c) * 2048 + li];
    adj[o] = s;
}

extern "C" void kernel_launch(void* const* d_in, const int* in_sizes, int n_in,
                              void* d_out, int out_size, void* d_ws, size_t ws_size,
                              hipStream_t stream) {
    const float* x = (const float*)d_in[0];
    const int* ei = (const int*)d_in[1];
    const int* batch = (const int*)d_in[2];
    const float* We = (const float*)d_in[3];
    const float* be = (const float*)d_in[4];
    const float* Wp = (const float*)d_in[5];
    const float* bp = (const float*)d_in[6];
    float* out = (float*)d_out;  // [adj 256*256 | h 256*128]

    char* w = (char*)d_ws;
    auto alloc = [&](size_t bytes) -> char* {
        char* p = w;
        w += (bytes + 255) & ~(size_t)255;
        return p;
    };
    unsigned short* xhi = (unsigned short*)alloc((size_t)N_ * 128 * 2);
    unsigned short* xlo = (unsigned short*)alloc((size_t)N_ * 128 * 2);
    unsigned short* nhi = (unsigned short*)alloc((size_t)N_ * 128 * 2);
    unsigned short* nlo = (unsigned short*)alloc((size_t)N_ * 128 * 2);
    unsigned short* WThi = (unsigned short*)alloc((size_t)JTOT * KTOT * 2);
    unsigned short* WTlo = (unsigned short*)alloc((size_t)JTOT * KTOT * 2);
    float* embed = (float*)alloc((size_t)N_ * 128 * 4);
    float* plog = (float*)alloc((size_t)N_ * 256 * 4);
    float* r8 = (float*)alloc((size_t)N_ * 8 * 4);
    unsigned short* r8b = (unsigned short*)alloc((size_t)N_ * 8 * 2);
    float* bias = (float*)alloc(JTOT * 4);
    int* deg = (int*)alloc((size_t)N_ * 4);
    int* rowStart = (int*)alloc((size_t)(N_ + 1) * 4);
    int* rowFill = (int*)alloc((size_t)N_ * 4);
    int2* csr = (int2*)alloc((size_t)E_ * 8);
    int* blockSum = (int*)alloc(NB_SCAN * 4);
    int* blockOff = (int*)alloc(NB_SCAN * 4);
    float* partH = (float*)alloc((size_t)B_ * HCHUNK * 1024 * 4);
    float* partAdj = (float*)alloc((size_t)B_ * ACHUNK * 2048 * 4);

    (void)hipMemsetAsync(deg, 0, (size_t)N_ * 4, stream);

    k_hist<<<(E_ + 255) / 256, 256, 0, stream>>>(ei, deg);
    k_scan_a<<<NB_SCAN, 256, 0, stream>>>(deg, blockSum);
    k_scan_b<<<1, 256, 0, stream>>>(blockSum, blockOff);
    k_scan_c<<<NB_SCAN, 256, 0, stream>>>(deg, blockOff, rowStart, rowFill);
    k_scatter<<<(E_ + 255) / 256, 256, 0, stream>>>(ei, rowFill, csr);
    k_convx<<<(N_ * 128 / 4 + 255) / 256, 256, 0, stream>>>(x, xhi, xlo);
    k_agg<<<(N_ + 3) / 4, 256, 0, stream>>>(x, rowStart, csr, nhi, nlo);
    k_prep<<<(JTOT * KTOT + 255) / 256, 256, 0, stream>>>(We, be, Wp, bp, WThi, WTlo, bias);
    dim3 gg((N_ + 127) / 128, JTOT / 128);
    k_gemm<<<gg, 256, 0, stream>>>(xhi, xlo, nhi, nlo, WThi, WTlo, bias, embed, plog);
    k_r<<<(N_ + 3) / 4, 256, 0, stream>>>(plog, batch, r8, r8b);
    dim3 hg(B_, HCHUNK);
    k_h_part<<<hg, 256, 0, stream>>>(embed, r8, partH);
    k_h_red<<<(256 * 128 + 255) / 256, 256, 0, stream>>>(partH, out + 256 * 256);
    dim3 ag(B_, ACHUNK);
    k_adjm<<<ag, 256, 0, stream>>>(rowStart, csr, r8b, partAdj);
    k_adj_red<<<(256 * 256 + 255) / 256, 256, 0, stream>>>(partAdj, out);
}

// Round 10
// 359.164 us; speedup vs baseline: 2.0229x; 1.0117x over previous
//
#include <hip/hip_runtime.h>
#include <hip/hip_bf16.h>

#define N_ 50000
#define E_ 800000
#define IN_ 128
#define OUT_ 128
#define ASSIGN_ 256
#define B_ 32
#define KTOT 256     // 2*IN
#define JTOT 384     // OUT + ASSIGN
#define HCHUNK 16
#define ACHUNK 16
#define AST 72       // k_adjm LDS row stride in u16
#define NB_SCAN ((N_ + 255) / 256)   // 196

typedef __attribute__((ext_vector_type(8))) short short8;
typedef __attribute__((ext_vector_type(4))) float f32x4;
typedef __attribute__((ext_vector_type(4))) unsigned short ushort4v;
typedef __attribute__((ext_vector_type(2))) unsigned short ushort2v;
typedef unsigned short u16;

struct HL { unsigned short h, l; };

__device__ inline unsigned short f2bf(float v) {
    union { float f; unsigned u; } a;
    a.f = v;
    unsigned r = a.u + 0x7fff + ((a.u >> 16) & 1);  // RNE
    return (unsigned short)(r >> 16);
}
__device__ inline float bf2f(unsigned short b) {
    union { unsigned u; float f; } a;
    a.u = ((unsigned)b) << 16;
    return a.f;
}
__device__ inline HL split2(float v) {
    HL r;
    r.h = f2bf(v);
    r.l = f2bf(v - bf2f(r.h));
    return r;
}

// ---------------- histogram: deg[dst]++ ----------------
__global__ void k_hist(const int* __restrict__ ei, int* __restrict__ deg) {
    int e = blockIdx.x * 256 + threadIdx.x;
    if (e < E_) atomicAdd(&deg[ei[E_ + e]], 1);
}

// ---------------- multi-block exclusive scan: deg -> rowStart/rowFill ----------------
__global__ __launch_bounds__(256) void k_scan_a(const int* __restrict__ deg,
                                                int* __restrict__ blockSum) {
    __shared__ int sh[256];
    int t = threadIdx.x;
    int i = blockIdx.x * 256 + t;
    sh[t] = (i < N_) ? deg[i] : 0;
    __syncthreads();
    for (int off = 128; off; off >>= 1) {
        if (t < off) sh[t] += sh[t + off];
        __syncthreads();
    }
    if (t == 0) blockSum[blockIdx.x] = sh[0];
}

__global__ __launch_bounds__(256) void k_scan_b(const int* __restrict__ blockSum,
                                                int* __restrict__ blockOff) {
    __shared__ int sh[256];
    int t = threadIdx.x;
    sh[t] = (t < NB_SCAN) ? blockSum[t] : 0;
    __syncthreads();
    for (int off = 1; off < 256; off <<= 1) {
        int x = sh[t];
        int add = (t >= off) ? sh[t - off] : 0;
        __syncthreads();
        sh[t] = x + add;
        __syncthreads();
    }
    if (t < NB_SCAN) blockOff[t] = (t == 0) ? 0 : sh[t - 1];
}

__global__ __launch_bounds__(256) void k_scan_c(const int* __restrict__ deg,
                                                const int* __restrict__ blockOff,
                                                int* __restrict__ rowStart,
                                                int* __restrict__ rowFill) {
    __shared__ int sh[256];
    int t = threadIdx.x;
    int i = blockIdx.x * 256 + t;
    int v = (i < N_) ? deg[i] : 0;
    sh[t] = v;
    __syncthreads();
    for (int off = 1; off < 256; off <<= 1) {
        int x = sh[t];
        int add = (t >= off) ? sh[t - off] : 0;
        __syncthreads();
        sh[t] = x + add;
        __syncthreads();
    }
    int excl = blockOff[blockIdx.x] + ((t == 0) ? 0 : sh[t - 1]);
    if (i < N_) {
        rowStart[i] = excl;
        rowFill[i] = excl;
    }
    if (i == 0) rowStart[N_] = E_;
}

// ---------------- scatter edges into CSR-by-dst, packed (src,dst) ----------------
__global__ void k_scatter(const int* __restrict__ ei, int* __restrict__ rowFill,
                          int2* __restrict__ csr) {
    int e = blockIdx.x * 256 + threadIdx.x;
    if (e >= E_) return;
    int s = ei[e], d = ei[E_ + e];
    int p = atomicAdd(&rowFill[d], 1);
    csr[p] = make_int2(s, d);
}

// ---------------- neigh mean -> bf16 hi/lo (one wave per node) ------
__global__ __launch_bounds__(256) void k_agg(const float* __restrict__ x,
                                             const int* __restrict__ rowStart,
                                             const int2* __restrict__ csr,
                                             unsigned short* __restrict__ nhi,
                                             unsigned short* __restrict__ nlo) {
    int node = blockIdx.x * 4 + (threadIdx.x >> 6);
    int lane = threadIdx.x & 63;
    if (node >= N_) return;
    int a = rowStart[node], bnd = rowStart[node + 1];
    float ax = 0.f, ay = 0.f;
    int j = a;
    for (; j + 1 < bnd; j += 2) {
        int s0 = csr[j].x, s1 = csr[j + 1].x;
        float2 v0 = *(const float2*)(x + s0 * 128 + lane * 2);
        float2 v1 = *(const float2*)(x + s1 * 128 + lane * 2);
        ax += v0.x + v1.x;
        ay += v0.y + v1.y;
    }
    if (j < bnd) {
        int s0 = csr[j].x;
        float2 v0 = *(const float2*)(x + s0 * 128 + lane * 2);
        ax += v0.x;
        ay += v0.y;
    }
    float inv = 1.0f / (float)max(bnd - a, 1);
    ax *= inv;
    ay *= inv;
    HL hx = split2(ax), hy = split2(ay);
    ushort2v h, l;
    h.x = hx.h; h.y = hy.h;
    l.x = hx.l; l.y = hy.l;
    *(ushort2v*)(nhi + node * 128 + lane * 2) = h;
    *(ushort2v*)(nlo + node * 128 + lane * 2) = l;
}

// ---------------- x -> bf16 hi/lo ----------------
__global__ __launch_bounds__(256) void k_convx(const float* __restrict__ x,
                                               unsigned short* __restrict__ xhi,
                                               unsigned short* __restrict__ xlo) {
    int i4 = (blockIdx.x * 256 + threadIdx.x) * 4;
    if (i4 >= N_ * 128) return;
    float4 v = *(const float4*)(x + i4);
    HL a = split2(v.x), b = split2(v.y), c = split2(v.z), d = split2(v.w);
    ushort4v h, l;
    h.x = a.h; h.y = b.h; h.z = c.h; h.w = d.h;
    l.x = a.l; l.y = b.l; l.z = c.l; l.w = d.l;
    *(ushort4v*)(xhi + i4) = h;
    *(ushort4v*)(xlo + i4) = l;
}

// ---------------- W transposed -> bf16 hi/lo WT[j][k], plus bias ----------------
__global__ void k_prep(const float* __restrict__ We, const float* __restrict__ be,
                       const float* __restrict__ Wp, const float* __restrict__ bp,
                       unsigned short* __restrict__ WThi, unsigned short* __restrict__ WTlo,
                       float* __restrict__ bias) {
    int idx = blockIdx.x * 256 + threadIdx.x;
    if (idx < JTOT * KTOT) {
        int j = idx / KTOT, k = idx - j * KTOT;
        float v = (j < 128) ? We[k * 128 + j] : Wp[k * 256 + (j - 128)];
        HL s = split2(v);
        WThi[idx] = s.h;
        WTlo[idx] = s.l;
    }
    if (idx < JTOT) bias[idx] = (idx < 128) ? be[idx] : bp[idx - 128];
}

// ---------------- MFMA GEMM: embed cols = bf16x3 split, pool cols = 1-pass ----------------
// block tile 128x128, 4 waves (2x2), wave tile 64x64 = 4x4 mfma_16x16x32 tiles, BK=32
// VGPR staging (compiler software-pipelines global loads across the barrier;
// global_load_lds regressed here — R9 post-mortem).
#define LDA 40  // 80 B rows
__global__ __launch_bounds__(256) void k_gemm(const unsigned short* __restrict__ xhi,
                                              const unsigned short* __restrict__ xlo,
                                              const unsigned short* __restrict__ nhi,
                                              const unsigned short* __restrict__ nlo,
                                              const unsigned short* __restrict__ WThi,
                                              const unsigned short* __restrict__ WTlo,
                                              const float* __restrict__ bias,
                                              float* __restrict__ embed,
                                              float* __restrict__ plog) {
    __shared__ u16 Ah[128][LDA], Al[128][LDA], Bh[128][LDA], Bl[128][LDA];
    int t = threadIdx.x;
    int wave = t >> 6, lane = t & 63;
    int wm = wave >> 1, wn = wave & 1;
    int q = lane >> 4, lr = lane & 15;
    int row0 = blockIdx.x * 128;
    int col0 = blockIdx.y * 128;
    const bool three = (col0 < 128);  // embed block: full bf16x3 precision

    f32x4 acc[4][4] = {};

    int sm = t >> 1;             // row within tile
    int kc = (t & 1) * 16;       // 0 or 16

    for (int kt = 0; kt < KTOT; kt += 32) {
        const u16* Ah_src = (kt < 128) ? xhi : nhi;
        const u16* Al_src = (kt < 128) ? xlo : nlo;
        int kb = (kt & 127) + kc;
        int node = row0 + sm;
        short8 vh0 = {}, vh1 = {};
        if (node < N_) {
            const short8* ph = (const short8*)(Ah_src + (size_t)node * 128 + kb);
            vh0 = ph[0]; vh1 = ph[1];
        }
        *(short8*)&Ah[sm][kc] = vh0;
        *(short8*)&Ah[sm][kc + 8] = vh1;
        if (three) {
            short8 vl0 = {}, vl1 = {};
            if (node < N_) {
                const short8* pl = (const short8*)(Al_src + (size_t)node * 128 + kb);
                vl0 = pl[0]; vl1 = pl[1];
            }
            *(short8*)&Al[sm][kc] = vl0;
            *(short8*)&Al[sm][kc + 8] = vl1;
        }
        {
            int jj = col0 + sm;
            const short8* ph = (const short8*)(WThi + (size_t)jj * 256 + kt + kc);
            short8 wh0 = ph[0], wh1 = ph[1];
            *(short8*)&Bh[sm][kc] = wh0;
            *(short8*)&Bh[sm][kc + 8] = wh1;
            if (three) {
                const short8* pl = (const short8*)(WTlo + (size_t)jj * 256 + kt + kc);
                short8 wl0 = pl[0], wl1 = pl[1];
                *(short8*)&Bl[sm][kc] = wl0;
                *(short8*)&Bl[sm][kc + 8] = wl1;
            }
        }
        __syncthreads();

        short8 afh[4], afl[4] = {};
#pragma unroll
        for (int mi = 0; mi < 4; mi++) {
            int r = wm * 64 + mi * 16 + lr;
            afh[mi] = *(const short8*)&Ah[r][q * 8];
        }
        if (three) {
#pragma unroll
            for (int mi = 0; mi < 4; mi++) {
                int r = wm * 64 + mi * 16 + lr;
                afl[mi] = *(const short8*)&Al[r][q * 8];
            }
        }
#pragma unroll
        for (int ni = 0; ni < 4; ni++) {
            int r = wn * 64 + ni * 16 + lr;
            short8 bfh = *(const short8*)&Bh[r][q * 8];
#pragma unroll
            for (int mi = 0; mi < 4; mi++)
                acc[mi][ni] = __builtin_amdgcn_mfma_f32_16x16x32_bf16(afh[mi], bfh, acc[mi][ni], 0, 0, 0);
            if (three) {
                short8 bfl = *(const short8*)&Bl[r][q * 8];
#pragma unroll
                for (int mi = 0; mi < 4; mi++) {
                    acc[mi][ni] = __builtin_amdgcn_mfma_f32_16x16x32_bf16(afh[mi], bfl, acc[mi][ni], 0, 0, 0);
                    acc[mi][ni] = __builtin_amdgcn_mfma_f32_16x16x32_bf16(afl[mi], bfh, acc[mi][ni], 0, 0, 0);
                }
            }
        }
        __syncthreads();
    }

    // epilogue: C/D layout col=lane&15, row=(lane>>4)*4+reg
#pragma unroll
    for (int ni = 0; ni < 4; ni++) {
        int col = col0 + wn * 64 + ni * 16 + lr;
        float bj = bias[col];
#pragma unroll
        for (int mi = 0; mi < 4; mi++) {
            int rbase = row0 + wm * 64 + mi * 16 + q * 4;
#pragma unroll
            for (int r = 0; r < 4; r++) {
                int row = rbase + r;
                if (row >= N_) continue;
                float v = acc[mi][ni][r] + bj;
                if (col < 128)
                    embed[(size_t)row * 128 + col] = v;
                else
                    plog[(size_t)row * 256 + (col - 128)] = v;
            }
        }
    }
}

// ---------------- double softmax -> compact r8[N][8] (fp32 + bf16 copy) ----------------
__global__ __launch_bounds__(256) void k_r(const float* __restrict__ plog,
                                           const int* __restrict__ batch,
                                           float* __restrict__ r8,
                                           unsigned short* __restrict__ r8b) {
    int node = blockIdx.x * 4 + (threadIdx.x >> 6);
    int lane = threadIdx.x & 63;
    if (node >= N_) return;
    float4 p = *(const float4*)(plog + node * 256 + lane * 4);
    float m = fmaxf(fmaxf(p.x, p.y), fmaxf(p.z, p.w));
    for (int off = 32; off; off >>= 1) m = fmaxf(m, __shfl_xor(m, off, 64));
    float s = expf(p.x - m) + expf(p.y - m) + expf(p.z - m) + expf(p.w - m);
    for (int off = 32; off; off >>= 1) s += __shfl_xor(s, off, 64);
    int g = batch[node];
    float v = 0.f;
    if (lane < 8) v = expf(plog[node * 256 + g * 8 + lane] - m) / s;
    float M2 = v;
    for (int off = 4; off; off >>= 1) M2 = fmaxf(M2, __shfl_xor(M2, off, 64));
    float e = expf(v - M2);
    float Sg = e;
    for (int off = 4; off; off >>= 1) Sg += __shfl_xor(Sg, off, 64);
    float D2 = Sg + 248.0f * expf(-M2);
    float r = e / (Sg + 1e-13f * D2);
    if (lane < 8) {
        r8[node * 8 + lane] = r;
        r8b[node * 8 + lane] = f2bf(r);
    }
}

// ---------------- h partials ----------------
__global__ __launch_bounds__(256) void k_h_part(const float* __restrict__ embed,
                                                const float* __restrict__ r8,
                                                float* __restrict__ partH) {
    int g = blockIdx.x;
    int c = blockIdx.y;
    int t = threadIdx.x;
    int o = t & 127, half = t >> 7;
    int n0g = (g * N_ + 31) >> 5;
    int n1g = ((g + 1) * N_ + 31) >> 5;
    int len = n1g - n0g;
    int a = n0g + (len * c) / HCHUNK;
    int b = n0g + (len * (c + 1)) / HCHUNK;
    float a0 = 0.f, a1 = 0.f, a2 = 0.f, a3 = 0.f;
#pragma unroll 4
    for (int n = a; n < b; n++) {
        float e = embed[n * 128 + o];
        const float* rr = r8 + n * 8 + half;
        a0 += rr[0] * e;
        a1 += rr[2] * e;
        a2 += rr[4] * e;
        a3 += rr[6] * e;
    }
    float* pb = partH + (g * HCHUNK + c) * 1024;
    pb[(half + 0) * 128 + o] = a0;
    pb[(half + 2) * 128 + o] = a1;
    pb[(half + 4) * 128 + o] = a2;
    pb[(half + 6) * 128 + o] = a3;
}

// ---------------- h reduce ----------------
__global__ __launch_bounds__(256) void k_h_red(const float* __restrict__ partH,
                                               float* __restrict__ out_h) {
    int idx = blockIdx.x * 256 + threadIdx.x;
    if (idx >= 256 * 128) return;
    int g = idx >> 10;
    int local = idx & 1023;
    float s = 0.f;
#pragma unroll
    for (int c = 0; c < HCHUNK; c++) s += partH[(g * HCHUNK + c) * 1024 + local];
    out_h[idx] = s;
}

// ---------------- adj via MFMA over edge tiles ----------------
__global__ __launch_bounds__(256) void k_adjm(const int* __restrict__ rowStart,
                                              const int2* __restrict__ csr,
                                              const unsigned short* __restrict__ r8b,
                                              float* __restrict__ partAdj) {
    __shared__ __align__(16) unsigned short Ab[256 * AST];  // [col=gs*8+a][e]
    __shared__ __align__(16) unsigned short Bb[16 * AST];   // [n=b][e]
    int gd = blockIdx.x, c = blockIdx.y;
    int t = threadIdx.x;
    int wave = t >> 6, lane = t & 63;
    int q = lane >> 4, lr = lane & 15;
    int n0g = (gd * N_ + 31) >> 5;
    int n1g = ((gd + 1) * N_ + 31) >> 5;
    int len = n1g - n0g;
    int na = n0g + (len * c) / ACHUNK;
    int nb = n0g + (len * (c + 1)) / ACHUNK;
    int j0 = rowStart[na], j1 = rowStart[nb];

    uint4 z = {0, 0, 0, 0};
    if (t < 144) *(uint4*)&Bb[t * 8] = z;

    f32x4 acc[4] = {};
    int el = t >> 2;   // edge slot 0..63
    int ap = t & 3;    // value-pair 0..3

    for (int jt = j0; jt < j1; jt += 64) {
        __syncthreads();
#pragma unroll
        for (int i = 0; i < 9; i++) {
            int o = (i * 256 + t) * 8;
            *(uint4*)&Ab[o] = z;
        }
        if (t < 72) *(uint4*)&Bb[t * 8] = z;
        __syncthreads();
        int j = jt + el;
        if (j < j1) {
            int2 sd = csr[j];
            int s = sd.x, d = sd.y;
            int gs = (s * B_) / N_;
            unsigned sv = *(const unsigned*)(r8b + s * 8 + ap * 2);
            unsigned dv = *(const unsigned*)(r8b + d * 8 + ap * 2);
            int ca = gs * 8 + ap * 2;
            Ab[ca * AST + el] = (unsigned short)sv;
            Ab[(ca + 1) * AST + el] = (unsigned short)(sv >> 16);
            Bb[(ap * 2) * AST + el] = (unsigned short)dv;
            Bb[(ap * 2 + 1) * AST + el] = (unsigned short)(dv >> 16);
        }
        __syncthreads();
        short8 bf0 = *(const short8*)&Bb[lr * AST + q * 8];
        short8 bf1 = *(const short8*)&Bb[lr * AST + 32 + q * 8];
#pragma unroll
        for (int mi = 0; mi < 4; mi++) {
            int col = (wave * 4 + mi) * 16 + lr;
            short8 a0 = *(const short8*)&Ab[col * AST + q * 8];
            short8 a1 = *(const short8*)&Ab[col * AST + 32 + q * 8];
            acc[mi] = __builtin_amdgcn_mfma_f32_16x16x32_bf16(a0, bf0, acc[mi], 0, 0, 0);
            acc[mi] = __builtin_amdgcn_mfma_f32_16x16x32_bf16(a1, bf1, acc[mi], 0, 0, 0);
        }
    }

    float* pb = partAdj + (gd * ACHUNK + c) * 2048;
    if (lr < 8) {
#pragma unroll
        for (int mi = 0; mi < 4; mi++) {
            int mbase = (wave * 4 + mi) * 16 + q * 4;
#pragma unroll
            for (int r = 0; r < 4; r++)
                pb[(mbase + r) * 8 + lr] = acc[mi][r];
        }
    }
}

// ---------------- adj reduce ----------------
__global__ __launch_bounds__(256) void k_adj_red(const float* __restrict__ partAdj,
                                                 float* __restrict__ adj) {
    int o = blockIdx.x * 256 + threadIdx.x;
    if (o >= 256 * 256) return;
    int row = o >> 8, col = o & 255;
    int gd = col >> 3, b = col & 7;
    int li = row * 8 + b;
    float s = 0.f;
#pragma unroll
    for (int c = 0; c < ACHUNK; c++) s += partAdj[(gd * ACHUNK + c) * 2048 + li];
    adj[o] = s;
}

extern "C" void kernel_launch(void* const* d_in, const int* in_sizes, int n_in,
                              void* d_out, int out_size, void* d_ws, size_t ws_size,
                              hipStream_t stream) {
    const float* x = (const float*)d_in[0];
    const int* ei = (const int*)d_in[1];
    const int* batch = (const int*)d_in[2];
    const float* We = (const float*)d_in[3];
    const float* be = (const float*)d_in[4];
    const float* Wp = (const float*)d_in[5];
    const float* bp = (const float*)d_in[6];
    float* out = (float*)d_out;  // [adj 256*256 | h 256*128]

    char* w = (char*)d_ws;
    auto alloc = [&](size_t bytes) -> char* {
        char* p = w;
        w += (bytes + 255) & ~(size_t)255;
        return p;
    };
    unsigned short* xhi = (unsigned short*)alloc((size_t)N_ * 128 * 2);
    unsigned short* xlo = (unsigned short*)alloc((size_t)N_ * 128 * 2);
    unsigned short* nhi = (unsigned short*)alloc((size_t)N_ * 128 * 2);
    unsigned short* nlo = (unsigned short*)alloc((size_t)N_ * 128 * 2);
    unsigned short* WThi = (unsigned short*)alloc((size_t)JTOT * KTOT * 2);
    unsigned short* WTlo = (unsigned short*)alloc((size_t)JTOT * KTOT * 2);
    float* embed = (float*)alloc((size_t)N_ * 128 * 4);
    float* plog = (float*)alloc((size_t)N_ * 256 * 4);
    float* r8 = (float*)alloc((size_t)N_ * 8 * 4);
    unsigned short* r8b = (unsigned short*)alloc((size_t)N_ * 8 * 2);
    float* bias = (float*)alloc(JTOT * 4);
    int* deg = (int*)alloc((size_t)N_ * 4);
    int* rowStart = (int*)alloc((size_t)(N_ + 1) * 4);
    int* rowFill = (int*)alloc((size_t)N_ * 4);
    int2* csr = (int2*)alloc((size_t)E_ * 8);
    int* blockSum = (int*)alloc(NB_SCAN * 4);
    int* blockOff = (int*)alloc(NB_SCAN * 4);
    float* partH = (float*)alloc((size_t)B_ * HCHUNK * 1024 * 4);
    float* partAdj = (float*)alloc((size_t)B_ * ACHUNK * 2048 * 4);

    (void)hipMemsetAsync(deg, 0, (size_t)N_ * 4, stream);

    k_hist<<<(E_ + 255) / 256, 256, 0, stream>>>(ei, deg);
    k_scan_a<<<NB_SCAN, 256, 0, stream>>>(deg, blockSum);
    k_scan_b<<<1, 256, 0, stream>>>(blockSum, blockOff);
    k_scan_c<<<NB_SCAN, 256, 0, stream>>>(deg, blockOff, rowStart, rowFill);
    k_scatter<<<(E_ + 255) / 256, 256, 0, stream>>>(ei, rowFill, csr);
    k_convx<<<(N_ * 128 / 4 + 255) / 256, 256, 0, stream>>>(x, xhi, xlo);
    k_agg<<<(N_ + 3) / 4, 256, 0, stream>>>(x, rowStart, csr, nhi, nlo);
    k_prep<<<(JTOT * KTOT + 255) / 256, 256, 0, stream>>>(We, be, Wp, bp, WThi, WTlo, bias);
    dim3 gg((N_ + 127) / 128, JTOT / 128);
    k_gemm<<<gg, 256, 0, stream>>>(xhi, xlo, nhi, nlo, WThi, WTlo, bias, embed, plog);
    k_r<<<(N_ + 3) / 4, 256, 0, stream>>>(plog, batch, r8, r8b);
    dim3 hg(B_, HCHUNK);
    k_h_part<<<hg, 256, 0, stream>>>(embed, r8, partH);
    k_h_red<<<(256 * 128 + 255) / 256, 256, 0, stream>>>(partH, out + 256 * 256);
    dim3 ag(B_, ACHUNK);
    k_adjm<<<ag, 256, 0, stream>>>(rowStart, csr, r8b, partAdj);
    k_adj_red<<<(256 * 256 + 255) / 256, 256, 0, stream>>>(partAdj, out);
}

// Round 11
// 352.886 us; speedup vs baseline: 2.0589x; 1.0178x over previous
//
#include <hip/hip_runtime.h>
#include <hip/hip_bf16.h>

#define N_ 50000
#define E_ 800000
#define IN_ 128
#define OUT_ 128
#define ASSIGN_ 256
#define B_ 32
#define KTOT 256     // 2*IN
#define JTOT 384     // OUT + ASSIGN
#define HCHUNK 16
#define ACHUNK 16
#define AST 72       // k_adjm LDS row stride in u16
#define NB_SCAN ((N_ + 255) / 256)   // 196

typedef __attribute__((ext_vector_type(8))) short short8;
typedef __attribute__((ext_vector_type(4))) float f32x4;
typedef __attribute__((ext_vector_type(4))) unsigned short ushort4v;
typedef __attribute__((ext_vector_type(2))) unsigned short ushort2v;
typedef unsigned short u16;

struct HL { unsigned short h, l; };

__device__ inline unsigned short f2bf(float v) {
    union { float f; unsigned u; } a;
    a.f = v;
    unsigned r = a.u + 0x7fff + ((a.u >> 16) & 1);  // RNE
    return (unsigned short)(r >> 16);
}
__device__ inline float bf2f(unsigned short b) {
    union { unsigned u; float f; } a;
    a.u = ((unsigned)b) << 16;
    return a.f;
}
__device__ inline HL split2(float v) {
    HL r;
    r.h = f2bf(v);
    r.l = f2bf(v - bf2f(r.h));
    return r;
}

// ---------------- histogram: deg[dst]++ ----------------
__global__ void k_hist(const int* __restrict__ ei, int* __restrict__ deg) {
    int e = blockIdx.x * 256 + threadIdx.x;
    if (e < E_) atomicAdd(&deg[ei[E_ + e]], 1);
}

// ---------------- multi-block exclusive scan: deg -> rowStart/rowFill ----------------
__global__ __launch_bounds__(256) void k_scan_a(const int* __restrict__ deg,
                                                int* __restrict__ blockSum) {
    __shared__ int sh[256];
    int t = threadIdx.x;
    int i = blockIdx.x * 256 + t;
    sh[t] = (i < N_) ? deg[i] : 0;
    __syncthreads();
    for (int off = 128; off; off >>= 1) {
        if (t < off) sh[t] += sh[t + off];
        __syncthreads();
    }
    if (t == 0) blockSum[blockIdx.x] = sh[0];
}

__global__ __launch_bounds__(256) void k_scan_b(const int* __restrict__ blockSum,
                                                int* __restrict__ blockOff) {
    __shared__ int sh[256];
    int t = threadIdx.x;
    sh[t] = (t < NB_SCAN) ? blockSum[t] : 0;
    __syncthreads();
    for (int off = 1; off < 256; off <<= 1) {
        int x = sh[t];
        int add = (t >= off) ? sh[t - off] : 0;
        __syncthreads();
        sh[t] = x + add;
        __syncthreads();
    }
    if (t < NB_SCAN) blockOff[t] = (t == 0) ? 0 : sh[t - 1];
}

__global__ __launch_bounds__(256) void k_scan_c(const int* __restrict__ deg,
                                                const int* __restrict__ blockOff,
                                                int* __restrict__ rowStart,
                                                int* __restrict__ rowFill) {
    __shared__ int sh[256];
    int t = threadIdx.x;
    int i = blockIdx.x * 256 + t;
    int v = (i < N_) ? deg[i] : 0;
    sh[t] = v;
    __syncthreads();
    for (int off = 1; off < 256; off <<= 1) {
        int x = sh[t];
        int add = (t >= off) ? sh[t - off] : 0;
        __syncthreads();
        sh[t] = x + add;
        __syncthreads();
    }
    int excl = blockOff[blockIdx.x] + ((t == 0) ? 0 : sh[t - 1]);
    if (i < N_) {
        rowStart[i] = excl;
        rowFill[i] = excl;
    }
    if (i == 0) rowStart[N_] = E_;
}

// ---------------- scatter edges into CSR-by-dst, packed (src,dst) ----------------
__global__ void k_scatter(const int* __restrict__ ei, int* __restrict__ rowFill,
                          int2* __restrict__ csr) {
    int e = blockIdx.x * 256 + threadIdx.x;
    if (e >= E_) return;
    int s = ei[e], d = ei[E_ + e];
    int p = atomicAdd(&rowFill[d], 1);
    csr[p] = make_int2(s, d);
}

// ---------------- neigh mean from bf16-hi gather -> bf16 hi/lo ------
// Gather xhi (256 B/row) instead of fp32 x (512 B/row): halves the
// bandwidth-bound random-gather stream (R10: 176 MB HBM fetch, 61 us).
// Precision: bf16 element rounding ~2^-9 rel -> neigh ~0.2% rel; adj/h
// contribution ~0.05 abs, within the 0.27 threshold.
__global__ __launch_bounds__(256) void k_agg(const unsigned short* __restrict__ xhi,
                                             const int* __restrict__ rowStart,
                                             const int2* __restrict__ csr,
                                             unsigned short* __restrict__ nhi,
                                             unsigned short* __restrict__ nlo) {
    int node = blockIdx.x * 4 + (threadIdx.x >> 6);
    int lane = threadIdx.x & 63;
    if (node >= N_) return;
    int a = rowStart[node], bnd = rowStart[node + 1];
    float ax = 0.f, ay = 0.f;
    int j = a;
    for (; j + 1 < bnd; j += 2) {
        int s0 = csr[j].x, s1 = csr[j + 1].x;
        unsigned v0 = *(const unsigned*)(xhi + (size_t)s0 * 128 + lane * 2);
        unsigned v1 = *(const unsigned*)(xhi + (size_t)s1 * 128 + lane * 2);
        ax += bf2f((unsigned short)v0) + bf2f((unsigned short)v1);
        ay += bf2f((unsigned short)(v0 >> 16)) + bf2f((unsigned short)(v1 >> 16));
    }
    if (j < bnd) {
        int s0 = csr[j].x;
        unsigned v0 = *(const unsigned*)(xhi + (size_t)s0 * 128 + lane * 2);
        ax += bf2f((unsigned short)v0);
        ay += bf2f((unsigned short)(v0 >> 16));
    }
    float inv = 1.0f / (float)max(bnd - a, 1);
    ax *= inv;
    ay *= inv;
    HL hx = split2(ax), hy = split2(ay);
    ushort2v h, l;
    h.x = hx.h; h.y = hy.h;
    l.x = hx.l; l.y = hy.l;
    *(ushort2v*)(nhi + (size_t)node * 128 + lane * 2) = h;
    *(ushort2v*)(nlo + (size_t)node * 128 + lane * 2) = l;
}

// ---------------- x -> bf16 hi/lo ----------------
__global__ __launch_bounds__(256) void k_convx(const float* __restrict__ x,
                                               unsigned short* __restrict__ xhi,
                                               unsigned short* __restrict__ xlo) {
    int i4 = (blockIdx.x * 256 + threadIdx.x) * 4;
    if (i4 >= N_ * 128) return;
    float4 v = *(const float4*)(x + i4);
    HL a = split2(v.x), b = split2(v.y), c = split2(v.z), d = split2(v.w);
    ushort4v h, l;
    h.x = a.h; h.y = b.h; h.z = c.h; h.w = d.h;
    l.x = a.l; l.y = b.l; l.z = c.l; l.w = d.l;
    *(ushort4v*)(xhi + i4) = h;
    *(ushort4v*)(xlo + i4) = l;
}

// ---------------- W transposed -> bf16 hi/lo WT[j][k], plus bias ----------------
__global__ void k_prep(const float* __restrict__ We, const float* __restrict__ be,
                       const float* __restrict__ Wp, const float* __restrict__ bp,
                       unsigned short* __restrict__ WThi, unsigned short* __restrict__ WTlo,
                       float* __restrict__ bias) {
    int idx = blockIdx.x * 256 + threadIdx.x;
    if (idx < JTOT * KTOT) {
        int j = idx / KTOT, k = idx - j * KTOT;
        float v = (j < 128) ? We[k * 128 + j] : Wp[k * 256 + (j - 128)];
        HL s = split2(v);
        WThi[idx] = s.h;
        WTlo[idx] = s.l;
    }
    if (idx < JTOT) bias[idx] = (idx < 128) ? be[idx] : bp[idx - 128];
}

// ---------------- MFMA GEMM: embed cols = bf16x3 split, pool cols = 1-pass ----------------
#define LDA 40  // 80 B rows
__global__ __launch_bounds__(256) void k_gemm(const unsigned short* __restrict__ xhi,
                                              const unsigned short* __restrict__ xlo,
                                              const unsigned short* __restrict__ nhi,
                                              const unsigned short* __restrict__ nlo,
                                              const unsigned short* __restrict__ WThi,
                                              const unsigned short* __restrict__ WTlo,
                                              const float* __restrict__ bias,
                                              float* __restrict__ embed,
                                              float* __restrict__ plog) {
    __shared__ u16 Ah[128][LDA], Al[128][LDA], Bh[128][LDA], Bl[128][LDA];
    int t = threadIdx.x;
    int wave = t >> 6, lane = t & 63;
    int wm = wave >> 1, wn = wave & 1;
    int q = lane >> 4, lr = lane & 15;
    int row0 = blockIdx.x * 128;
    int col0 = blockIdx.y * 128;
    const bool three = (col0 < 128);  // embed block: full bf16x3 precision

    f32x4 acc[4][4] = {};

    int sm = t >> 1;             // row within tile
    int kc = (t & 1) * 16;       // 0 or 16

    for (int kt = 0; kt < KTOT; kt += 32) {
        const u16* Ah_src = (kt < 128) ? xhi : nhi;
        const u16* Al_src = (kt < 128) ? xlo : nlo;
        int kb = (kt & 127) + kc;
        int node = row0 + sm;
        short8 vh0 = {}, vh1 = {};
        if (node < N_) {
            const short8* ph = (const short8*)(Ah_src + (size_t)node * 128 + kb);
            vh0 = ph[0]; vh1 = ph[1];
        }
        *(short8*)&Ah[sm][kc] = vh0;
        *(short8*)&Ah[sm][kc + 8] = vh1;
        if (three) {
            short8 vl0 = {}, vl1 = {};
            if (node < N_) {
                const short8* pl = (const short8*)(Al_src + (size_t)node * 128 + kb);
                vl0 = pl[0]; vl1 = pl[1];
            }
            *(short8*)&Al[sm][kc] = vl0;
            *(short8*)&Al[sm][kc + 8] = vl1;
        }
        {
            int jj = col0 + sm;
            const short8* ph = (const short8*)(WThi + (size_t)jj * 256 + kt + kc);
            short8 wh0 = ph[0], wh1 = ph[1];
            *(short8*)&Bh[sm][kc] = wh0;
            *(short8*)&Bh[sm][kc + 8] = wh1;
            if (three) {
                const short8* pl = (const short8*)(WTlo + (size_t)jj * 256 + kt + kc);
                short8 wl0 = pl[0], wl1 = pl[1];
                *(short8*)&Bl[sm][kc] = wl0;
                *(short8*)&Bl[sm][kc + 8] = wl1;
            }
        }
        __syncthreads();

        short8 afh[4], afl[4] = {};
#pragma unroll
        for (int mi = 0; mi < 4; mi++) {
            int r = wm * 64 + mi * 16 + lr;
            afh[mi] = *(const short8*)&Ah[r][q * 8];
        }
        if (three) {
#pragma unroll
            for (int mi = 0; mi < 4; mi++) {
                int r = wm * 64 + mi * 16 + lr;
                afl[mi] = *(const short8*)&Al[r][q * 8];
            }
        }
#pragma unroll
        for (int ni = 0; ni < 4; ni++) {
            int r = wn * 64 + ni * 16 + lr;
            short8 bfh = *(const short8*)&Bh[r][q * 8];
#pragma unroll
            for (int mi = 0; mi < 4; mi++)
                acc[mi][ni] = __builtin_amdgcn_mfma_f32_16x16x32_bf16(afh[mi], bfh, acc[mi][ni], 0, 0, 0);
            if (three) {
                short8 bfl = *(const short8*)&Bl[r][q * 8];
#pragma unroll
                for (int mi = 0; mi < 4; mi++) {
                    acc[mi][ni] = __builtin_amdgcn_mfma_f32_16x16x32_bf16(afh[mi], bfl, acc[mi][ni], 0, 0, 0);
                    acc[mi][ni] = __builtin_amdgcn_mfma_f32_16x16x32_bf16(afl[mi], bfh, acc[mi][ni], 0, 0, 0);
                }
            }
        }
        __syncthreads();
    }

    // epilogue: C/D layout col=lane&15, row=(lane>>4)*4+reg
#pragma unroll
    for (int ni = 0; ni < 4; ni++) {
        int col = col0 + wn * 64 + ni * 16 + lr;
        float bj = bias[col];
#pragma unroll
        for (int mi = 0; mi < 4; mi++) {
            int rbase = row0 + wm * 64 + mi * 16 + q * 4;
#pragma unroll
            for (int r = 0; r < 4; r++) {
                int row = rbase + r;
                if (row >= N_) continue;
                float v = acc[mi][ni][r] + bj;
                if (col < 128)
                    embed[(size_t)row * 128 + col] = v;
                else
                    plog[(size_t)row * 256 + (col - 128)] = v;
            }
        }
    }
}

// ---------------- double softmax -> compact r8[N][8] (fp32 + bf16 copy) ----------------
__global__ __launch_bounds__(256) void k_r(const float* __restrict__ plog,
                                           const int* __restrict__ batch,
                                           float* __restrict__ r8,
                                           unsigned short* __restrict__ r8b) {
    int node = blockIdx.x * 4 + (threadIdx.x >> 6);
    int lane = threadIdx.x & 63;
    if (node >= N_) return;
    float4 p = *(const float4*)(plog + node * 256 + lane * 4);
    float m = fmaxf(fmaxf(p.x, p.y), fmaxf(p.z, p.w));
    for (int off = 32; off; off >>= 1) m = fmaxf(m, __shfl_xor(m, off, 64));
    float s = expf(p.x - m) + expf(p.y - m) + expf(p.z - m) + expf(p.w - m);
    for (int off = 32; off; off >>= 1) s += __shfl_xor(s, off, 64);
    int g = batch[node];
    float v = 0.f;
    if (lane < 8) v = expf(plog[node * 256 + g * 8 + lane] - m) / s;
    float M2 = v;
    for (int off = 4; off; off >>= 1) M2 = fmaxf(M2, __shfl_xor(M2, off, 64));
    float e = expf(v - M2);
    float Sg = e;
    for (int off = 4; off; off >>= 1) Sg += __shfl_xor(Sg, off, 64);
    float D2 = Sg + 248.0f * expf(-M2);
    float r = e / (Sg + 1e-13f * D2);
    if (lane < 8) {
        r8[node * 8 + lane] = r;
        r8b[node * 8 + lane] = f2bf(r);
    }
}

// ---------------- h partials ----------------
__global__ __launch_bounds__(256) void k_h_part(const float* __restrict__ embed,
                                                const float* __restrict__ r8,
                                                float* __restrict__ partH) {
    int g = blockIdx.x;
    int c = blockIdx.y;
    int t = threadIdx.x;
    int o = t & 127, half = t >> 7;
    int n0g = (g * N_ + 31) >> 5;
    int n1g = ((g + 1) * N_ + 31) >> 5;
    int len = n1g - n0g;
    int a = n0g + (len * c) / HCHUNK;
    int b = n0g + (len * (c + 1)) / HCHUNK;
    float a0 = 0.f, a1 = 0.f, a2 = 0.f, a3 = 0.f;
#pragma unroll 4
    for (int n = a; n < b; n++) {
        float e = embed[n * 128 + o];
        const float* rr = r8 + n * 8 + half;
        a0 += rr[0] * e;
        a1 += rr[2] * e;
        a2 += rr[4] * e;
        a3 += rr[6] * e;
    }
    float* pb = partH + (g * HCHUNK + c) * 1024;
    pb[(half + 0) * 128 + o] = a0;
    pb[(half + 2) * 128 + o] = a1;
    pb[(half + 4) * 128 + o] = a2;
    pb[(half + 6) * 128 + o] = a3;
}

// ---------------- h reduce ----------------
__global__ __launch_bounds__(256) void k_h_red(const float* __restrict__ partH,
                                               float* __restrict__ out_h) {
    int idx = blockIdx.x * 256 + threadIdx.x;
    if (idx >= 256 * 128) return;
    int g = idx >> 10;
    int local = idx & 1023;
    float s = 0.f;
#pragma unroll
    for (int c = 0; c < HCHUNK; c++) s += partH[(g * HCHUNK + c) * 1024 + local];
    out_h[idx] = s;
}

// ---------------- adj via MFMA over edge tiles ----------------
__global__ __launch_bounds__(256) void k_adjm(const int* __restrict__ rowStart,
                                              const int2* __restrict__ csr,
                                              const unsigned short* __restrict__ r8b,
                                              float* __restrict__ partAdj) {
    __shared__ __align__(16) unsigned short Ab[256 * AST];  // [col=gs*8+a][e]
    __shared__ __align__(16) unsigned short Bb[16 * AST];   // [n=b][e]
    int gd = blockIdx.x, c = blockIdx.y;
    int t = threadIdx.x;
    int wave = t >> 6, lane = t & 63;
    int q = lane >> 4, lr = lane & 15;
    int n0g = (gd * N_ + 31) >> 5;
    int n1g = ((gd + 1) * N_ + 31) >> 5;
    int len = n1g - n0g;
    int na = n0g + (len * c) / ACHUNK;
    int nb = n0g + (len * (c + 1)) / ACHUNK;
    int j0 = rowStart[na], j1 = rowStart[nb];

    uint4 z = {0, 0, 0, 0};
    if (t < 144) *(uint4*)&Bb[t * 8] = z;

    f32x4 acc[4] = {};
    int el = t >> 2;   // edge slot 0..63
    int ap = t & 3;    // value-pair 0..3

    for (int jt = j0; jt < j1; jt += 64) {
        __syncthreads();
#pragma unroll
        for (int i = 0; i < 9; i++) {
            int o = (i * 256 + t) * 8;
            *(uint4*)&Ab[o] = z;
        }
        if (t < 72) *(uint4*)&Bb[t * 8] = z;
        __syncthreads();
        int j = jt + el;
        if (j < j1) {
            int2 sd = csr[j];
            int s = sd.x, d = sd.y;
            int gs = (s * B_) / N_;
            unsigned sv = *(const unsigned*)(r8b + s * 8 + ap * 2);
            unsigned dv = *(const unsigned*)(r8b + d * 8 + ap * 2);
            int ca = gs * 8 + ap * 2;
            Ab[ca * AST + el] = (unsigned short)sv;
            Ab[(ca + 1) * AST + el] = (unsigned short)(sv >> 16);
            Bb[(ap * 2) * AST + el] = (unsigned short)dv;
            Bb[(ap * 2 + 1) * AST + el] = (unsigned short)(dv >> 16);
        }
        __syncthreads();
        short8 bf0 = *(const short8*)&Bb[lr * AST + q * 8];
        short8 bf1 = *(const short8*)&Bb[lr * AST + 32 + q * 8];
#pragma unroll
        for (int mi = 0; mi < 4; mi++) {
            int col = (wave * 4 + mi) * 16 + lr;
            short8 a0 = *(const short8*)&Ab[col * AST + q * 8];
            short8 a1 = *(const short8*)&Ab[col * AST + 32 + q * 8];
            acc[mi] = __builtin_amdgcn_mfma_f32_16x16x32_bf16(a0, bf0, acc[mi], 0, 0, 0);
            acc[mi] = __builtin_amdgcn_mfma_f32_16x16x32_bf16(a1, bf1, acc[mi], 0, 0, 0);
        }
    }

    float* pb = partAdj + (gd * ACHUNK + c) * 2048;
    if (lr < 8) {
#pragma unroll
        for (int mi = 0; mi < 4; mi++) {
            int mbase = (wave * 4 + mi) * 16 + q * 4;
#pragma unroll
            for (int r = 0; r < 4; r++)
                pb[(mbase + r) * 8 + lr] = acc[mi][r];
        }
    }
}

// ---------------- adj reduce ----------------
__global__ __launch_bounds__(256) void k_adj_red(const float* __restrict__ partAdj,
                                                 float* __restrict__ adj) {
    int o = blockIdx.x * 256 + threadIdx.x;
    if (o >= 256 * 256) return;
    int row = o >> 8, col = o & 255;
    int gd = col >> 3, b = col & 7;
    int li = row * 8 + b;
    float s = 0.f;
#pragma unroll
    for (int c = 0; c < ACHUNK; c++) s += partAdj[(gd * ACHUNK + c) * 2048 + li];
    adj[o] = s;
}

extern "C" void kernel_launch(void* const* d_in, const int* in_sizes, int n_in,
                              void* d_out, int out_size, void* d_ws, size_t ws_size,
                              hipStream_t stream) {
    const float* x = (const float*)d_in[0];
    const int* ei = (const int*)d_in[1];
    const int* batch = (const int*)d_in[2];
    const float* We = (const float*)d_in[3];
    const float* be = (const float*)d_in[4];
    const float* Wp = (const float*)d_in[5];
    const float* bp = (const float*)d_in[6];
    float* out = (float*)d_out;  // [adj 256*256 | h 256*128]

    char* w = (char*)d_ws;
    auto alloc = [&](size_t bytes) -> char* {
        char* p = w;
        w += (bytes + 255) & ~(size_t)255;
        return p;
    };
    unsigned short* xhi = (unsigned short*)alloc((size_t)N_ * 128 * 2);
    unsigned short* xlo = (unsigned short*)alloc((size_t)N_ * 128 * 2);
    unsigned short* nhi = (unsigned short*)alloc((size_t)N_ * 128 * 2);
    unsigned short* nlo = (unsigned short*)alloc((size_t)N_ * 128 * 2);
    unsigned short* WThi = (unsigned short*)alloc((size_t)JTOT * KTOT * 2);
    unsigned short* WTlo = (unsigned short*)alloc((size_t)JTOT * KTOT * 2);
    float* embed = (float*)alloc((size_t)N_ * 128 * 4);
    float* plog = (float*)alloc((size_t)N_ * 256 * 4);
    float* r8 = (float*)alloc((size_t)N_ * 8 * 4);
    unsigned short* r8b = (unsigned short*)alloc((size_t)N_ * 8 * 2);
    float* bias = (float*)alloc(JTOT * 4);
    int* deg = (int*)alloc((size_t)N_ * 4);
    int* rowStart = (int*)alloc((size_t)(N_ + 1) * 4);
    int* rowFill = (int*)alloc((size_t)N_ * 4);
    int2* csr = (int2*)alloc((size_t)E_ * 8);
    int* blockSum = (int*)alloc(NB_SCAN * 4);
    int* blockOff = (int*)alloc(NB_SCAN * 4);
    float* partH = (float*)alloc((size_t)B_ * HCHUNK * 1024 * 4);
    float* partAdj = (float*)alloc((size_t)B_ * ACHUNK * 2048 * 4);

    (void)hipMemsetAsync(deg, 0, (size_t)N_ * 4, stream);

    k_hist<<<(E_ + 255) / 256, 256, 0, stream>>>(ei, deg);
    k_scan_a<<<NB_SCAN, 256, 0, stream>>>(deg, blockSum);
    k_scan_b<<<1, 256, 0, stream>>>(blockSum, blockOff);
    k_scan_c<<<NB_SCAN, 256, 0, stream>>>(deg, blockOff, rowStart, rowFill);
    k_scatter<<<(E_ + 255) / 256, 256, 0, stream>>>(ei, rowFill, csr);
    k_convx<<<(N_ * 128 / 4 + 255) / 256, 256, 0, stream>>>(x, xhi, xlo);
    k_agg<<<(N_ + 3) / 4, 256, 0, stream>>>(xhi, rowStart, csr, nhi, nlo);
    k_prep<<<(JTOT * KTOT + 255) / 256, 256, 0, stream>>>(We, be, Wp, bp, WThi, WTlo, bias);
    dim3 gg((N_ + 127) / 128, JTOT / 128);
    k_gemm<<<gg, 256, 0, stream>>>(xhi, xlo, nhi, nlo, WThi, WTlo, bias, embed, plog);
    k_r<<<(N_ + 3) / 4, 256, 0, stream>>>(plog, batch, r8, r8b);
    dim3 hg(B_, HCHUNK);
    k_h_part<<<hg, 256, 0, stream>>>(embed, r8, partH);
    k_h_red<<<(256 * 128 + 255) / 256, 256, 0, stream>>>(partH, out + 256 * 256);
    dim3 ag(B_, ACHUNK);
    k_adjm<<<ag, 256, 0, stream>>>(rowStart, csr, r8b, partAdj);
    k_adj_red<<<(256 * 256 + 255) / 256, 256, 0, stream>>>(partAdj, out);
}